// Round 5
// baseline (629.349 us; speedup 1.0000x reference)
//
#include <hip/hip_runtime.h>
#include <hip/hip_bf16.h>
#include <math.h>

#define NREL 8
#define LN_EPS 1e-5f
#define NEG_SLOPE 0.2f

typedef __hip_bfloat16 bf16;
typedef __attribute__((ext_vector_type(8))) short short8;
typedef __attribute__((ext_vector_type(4))) float floatx4;
typedef __attribute__((ext_vector_type(4))) unsigned int uintx4;

__device__ __forceinline__ unsigned int f2bu(float v) {
    bf16 t = __float2bfloat16(v);
    return (unsigned int)*reinterpret_cast<unsigned short*>(&t);
}

__device__ __forceinline__ float4 load4(const float* p) { return *(const float4*)p; }

__device__ __forceinline__ void fma8(float acc[8], float w, uint4 u) {
    union { unsigned int i; float f; } t;
    t.i = u.x << 16;          acc[0] = fmaf(w, t.f, acc[0]);
    t.i = u.x & 0xffff0000u;  acc[1] = fmaf(w, t.f, acc[1]);
    t.i = u.y << 16;          acc[2] = fmaf(w, t.f, acc[2]);
    t.i = u.y & 0xffff0000u;  acc[3] = fmaf(w, t.f, acc[3]);
    t.i = u.z << 16;          acc[4] = fmaf(w, t.f, acc[4]);
    t.i = u.z & 0xffff0000u;  acc[5] = fmaf(w, t.f, acc[5]);
    t.i = u.w << 16;          acc[6] = fmaf(w, t.f, acc[6]);
    t.i = u.w & 0xffff0000u;  acc[7] = fmaf(w, t.f, acc[7]);
}

__device__ __forceinline__ void async16(const void* g, void* l) {
    __builtin_amdgcn_global_load_lds(
        (const __attribute__((address_space(1))) void*)g,
        (__attribute__((address_space(3))) void*)l, 16, 0, 0);
}

// ---------------------------------------------------------------------------
// CSR build: count -> hierarchical scan -> fill (pk = (src<<3)|rel)
// ---------------------------------------------------------------------------
__global__ __launch_bounds__(256) void count_kernel(const int* __restrict__ dst,
                                                    int* __restrict__ cnt, int E) {
    int e = blockIdx.x * 256 + threadIdx.x;
    if (e < E) atomicAdd(&cnt[dst[e]], 1);
}

__global__ __launch_bounds__(1024) void scan1_kernel(const int* __restrict__ cnt,
                                                     int* __restrict__ rowptr,
                                                     int* __restrict__ bsum, int N) {
    __shared__ int sm[1024];
    int tid = threadIdx.x;
    int base = blockIdx.x * 1024;
    int v = (base + tid < N) ? cnt[base + tid] : 0;
    sm[tid] = v;
    __syncthreads();
    for (int off = 1; off < 1024; off <<= 1) {
        int t = (tid >= off) ? sm[tid - off] : 0;
        __syncthreads();
        sm[tid] += t;
        __syncthreads();
    }
    if (base + tid < N) rowptr[base + tid + 1] = sm[tid];
    if (tid == 1023) bsum[blockIdx.x] = sm[1023];
    if (blockIdx.x == 0 && tid == 0) rowptr[0] = 0;
}

__global__ __launch_bounds__(64) void scan2_kernel(int* __restrict__ bsum, int nb) {
    int lane = threadIdx.x;
    int v = (lane < nb) ? bsum[lane] : 0;
    for (int off = 1; off < 64; off <<= 1) {
        int t = __shfl_up(v, off, 64);
        if (lane >= off) v += t;
    }
    int ex = __shfl_up(v, 1, 64);
    if (lane == 0) ex = 0;
    if (lane < nb) bsum[lane] = ex;
}

__global__ __launch_bounds__(1024) void scan3_kernel(int* __restrict__ rowptr,
                                                     const int* __restrict__ bsum, int N) {
    int i = blockIdx.x * 1024 + threadIdx.x;
    if (i < N) rowptr[i + 1] += bsum[blockIdx.x];
}

__global__ __launch_bounds__(256) void fill_kernel(const int* __restrict__ src,
                                                   const int* __restrict__ dst,
                                                   const int* __restrict__ et,
                                                   const int* __restrict__ rowptr,
                                                   int* __restrict__ cursor,
                                                   int* __restrict__ pks, int E) {
    int e = blockIdx.x * 256 + threadIdx.x;
    if (e < E) {
        int d = dst[e];
        int pos = atomicAdd(&cursor[d], 1);
        pks[rowptr[d] + pos] = (src[e] << 3) | et[e];
    }
}

// ---------------------------------------------------------------------------
// x fp32 -> bf16 (vectorized)
// ---------------------------------------------------------------------------
__global__ __launch_bounds__(256) void convx_kernel(const float* __restrict__ x,
                                                    bf16* __restrict__ xb, int total4) {
    int i = blockIdx.x * 256 + threadIdx.x;
    if (i < total4) {
        float4 v = ((const float4*)x)[i];
        ushort4 o;
        o.x = (unsigned short)f2bu(v.x);
        o.y = (unsigned short)f2bu(v.y);
        o.z = (unsigned short)f2bu(v.z);
        o.w = (unsigned short)f2bu(v.w);
        ((ushort4*)xb)[i] = o;
    }
}

// ---------------------------------------------------------------------------
// Pack W fp32 [R][K][Nc] into MFMA-B-fragment order (hi bf16 only).
// ---------------------------------------------------------------------------
__global__ __launch_bounds__(256) void packw_kernel(const float* __restrict__ W,
                                                    bf16* __restrict__ hi,
                                                    int K, int Nc, int total) {
    int i = blockIdx.x * 256 + threadIdx.x;
    if (i >= total) return;
    int kk = i & 7;
    int t1 = i >> 3;
    int nl = t1 & 15;
    int t2 = t1 >> 4;
    int nt = t2 % (Nc / 16);
    int t3 = t2 / (Nc / 16);
    int q = t3 & 3;
    int t4 = t3 >> 2;
    int kt = t4 % (K / 32);
    int r = t4 / (K / 32);
    int k = kt * 32 + q * 8 + kk;
    int n = nt * 16 + nl;
    hi[i] = __float2bfloat16(W[((size_t)r * K + k) * Nc + n]);
}

// ---------------------------------------------------------------------------
// Precompute U[k][col] = sum_c W[r][k][h*64+c] * a_{sd}[h][c], packed in MFMA
// B-fragment order (col = r*2H + sd*H + h).
// ---------------------------------------------------------------------------
template <int HH>
__global__ __launch_bounds__(256) void prepu_kernel(const float* __restrict__ W,
                                                    const float* __restrict__ as_,
                                                    const float* __restrict__ ad_,
                                                    bf16* __restrict__ Up, int K) {
    constexpr int NCOL = NREL * 2 * HH;
    constexpr int JT = NCOL / 16;
    int idx = blockIdx.x * 256 + threadIdx.x;
    if (idx >= K * NCOL) return;
    int kk = idx & 7;
    int t1 = idx >> 3;
    int nl = t1 & 15;
    int t2 = t1 >> 4;
    int nt = t2 % JT;
    int t3 = t2 / JT;
    int q = t3 & 3;
    int kt = t3 >> 2;
    int k = kt * 32 + q * 8 + kk;
    int col = nt * 16 + nl;
    int r = col / (2 * HH);
    int rem = col % (2 * HH);
    int sd = rem / HH;
    int h = rem % HH;
    const float* a = (sd ? ad_ : as_) + h * 64;
    const float* w = W + ((size_t)r * K + k) * (HH * 64) + h * 64;
    float s = 0.f;
#pragma unroll
    for (int c = 0; c < 16; c++) {
        float4 wv4 = load4(w + c * 4);
        float4 av4 = load4(a + c * 4);
        s += wv4.x * av4.x + wv4.y * av4.y + wv4.z * av4.z + wv4.w * av4.w;
    }
    Up[idx] = __float2bfloat16(s);
}

// ---------------------------------------------------------------------------
// Big MFMA GEMM: 256x128 tile, 8 waves (4m x 2n), RING-3, one barrier/K-step.
// xw output written with NONTEMPORAL stores: the 200MB stream has zero cache
// reuse (agg re-fetches all of it from HBM), and the L2 write-allocate path
// is the modeled 2.1 TB/s cap that pinned all three prior schedules at 93us.
// ---------------------------------------------------------------------------
__global__ __launch_bounds__(512) void mfma_gemm_big(const bf16* __restrict__ A,
                                                     const bf16* __restrict__ Bh,
                                                     bf16* __restrict__ C,
                                                     int M, int K, int Nc) {
    const int gy = Nc / 128;          // 2
    const int nyr = gy * NREL;        // 16
    int id = blockIdx.x;
    int res = id & 7;
    int q = id >> 3;
    int j_ = q % nyr;
    int mg = q / nyr;
    int mt = mg * 8 + res;
    const int MBcnt = (M + 255) >> 8;
    if (mt >= MBcnt) return;
    const int m0 = mt * 256;
    const int y = j_ % gy;
    const int r = j_ / gy;
    const int n0 = y * 128;

    const int tid = threadIdx.x;
    const int wv = tid >> 6;
    const int lane = tid & 63;
    const int wm = wv & 3, wn = wv >> 2;
    const int ml = lane & 15, mq = lane >> 4;

    __shared__ __align__(16) short lsA[3][8192];    // 3 x 16KB A tiles
    __shared__ __align__(16) short lsBh[3][4096];   // 3 x 8KB B tiles

    floatx4 acc[4][4];
#pragma unroll
    for (int i = 0; i < 4; i++)
#pragma unroll
        for (int j = 0; j < 4; j++) acc[i][j] = (floatx4)(0.f);

    const int nkt = K >> 5;

    // A staging: 1024 slots (16KB), 2 per thread. slot = rgrp*256+it*64+qq*16+ml_
    const bf16* aptr[2];
    short* adst[2];
#pragma unroll
    for (int c = 0; c < 2; c++) {
        int idx = c * 512 + tid;
        int rgrp = idx >> 8;
        int it = (idx >> 6) & 3;
        int qq = (idx >> 4) & 3;
        int ml_ = idx & 15;
        int row = m0 + rgrp * 64 + it * 16 + ml_;
        row = row < M ? row : M - 1;
        aptr[c] = A + (size_t)row * K + qq * 8;
        adst[c] = &lsA[0][(c * 512 + wv * 64) * 8];
    }
    // B staging: 512 slots (8KB), 1 per thread. slot = qq*128 + nt*16 + nl
    const bf16* bptr;
    short* bdst;
    {
        int qq = tid >> 7;
        int rem = tid & 127;
        int nt = rem >> 4;
        int nl = rem & 15;
        bptr = Bh + (size_t)r * K * Nc +
               ((size_t)(qq * (Nc / 16) + (n0 >> 4) + nt) * 16 + nl) * 8;
        bdst = &lsBh[0][(wv * 64) * 8];
    }
    const size_t bstep = (size_t)32 * Nc;

#define STAGE_BIG(BUF)                                                         \
    {                                                                          \
        _Pragma("unroll")                                                      \
        for (int c = 0; c < 2; c++) {                                          \
            async16(aptr[c], adst[c] + (BUF) * 8192);                          \
            aptr[c] += 32;                                                     \
        }                                                                      \
        async16(bptr, bdst + (BUF) * 4096);                                    \
        bptr += bstep;                                                         \
    }

    // prologue: tiles 0,1 into buffers 0,1
    STAGE_BIG(0);
    STAGE_BIG(1);

    int cur = 0;
    for (int kt = 0; kt < nkt; kt++) {
        if (kt + 1 < nkt) {
            asm volatile("s_waitcnt vmcnt(3)" ::: "memory");
        } else {
            asm volatile("s_waitcnt vmcnt(0)" ::: "memory");
        }
        __builtin_amdgcn_s_barrier();

        if (kt + 2 < nkt) {
            int stg = (cur == 0) ? 2 : cur - 1;   // (cur+2)%3
            STAGE_BIG(stg);
        }

        short8 af[4];
#pragma unroll
        for (int i = 0; i < 4; i++)
            af[i] = *(const short8*)&lsA[cur][(wm * 256 + i * 64 + lane) * 8];

#pragma unroll
        for (int j = 0; j < 4; j++) {
            int ntl = wn * 4 + j;
            short8 bh = *(const short8*)&lsBh[cur][(mq * 128 + ntl * 16 + ml) * 8];
#pragma unroll
            for (int i = 0; i < 4; i++)
                acc[i][j] = __builtin_amdgcn_mfma_f32_16x16x32_bf16(af[i], bh, acc[i][j], 0, 0, 0);
        }
        cur = (cur == 2) ? 0 : cur + 1;
    }
#undef STAGE_BIG

    // ---- C store via XOR-swizzled LDS repack + NONTEMPORAL global stores ----
    {
        bf16* rep = (bf16*)lsA;                  // 64 x 128 bf16 = 16KB
#pragma unroll
        for (int i = 0; i < 4; i++) {
            __syncthreads();
#pragma unroll
            for (int j = 0; j < 4; j++) {
                int col = wn * 64 + j * 16 + ml;
#pragma unroll
                for (int reg = 0; reg < 4; reg++) {
                    int rrow = wm * 16 + mq * 4 + reg;
                    int blk = (col >> 3) ^ (((rrow >> 2) & 3) << 1);
                    rep[rrow * 128 + blk * 8 + (col & 7)] =
                        __float2bfloat16(acc[i][j][reg]);
                }
            }
            __syncthreads();
#pragma unroll
            for (int rr = 0; rr < 2; rr++) {
                int lrow = rr * 32 + (tid >> 4);
                int cblk = (tid & 15) ^ (((lrow >> 2) & 3) << 1);
                uintx4 v = *(const uintx4*)&rep[lrow * 128 + cblk * 8];
                int m = m0 + (lrow >> 4) * 64 + i * 16 + (lrow & 15);
                if (m < M)
                    __builtin_nontemporal_store(
                        v, (uintx4*)&C[((size_t)m * NREL + r) * Nc + n0 + (tid & 15) * 8]);
            }
        }
    }
}

// ---------------------------------------------------------------------------
// MFMA GEMM (128-tile, 4 waves) — layer-2 GEMM (BN=64). RING-3, one barrier.
// Cached stores kept: its 25.6MB output fits L2/L3 and agg_h1 re-reads it.
// ---------------------------------------------------------------------------
template <int BN>
__global__ __launch_bounds__(256) void mfma_gemm(const bf16* __restrict__ A,
                                                 const bf16* __restrict__ Bh,
                                                 bf16* __restrict__ C,
                                                 int M, int K, int Nc) {
    const int gy = Nc / BN;
    const int nyr = gy * NREL;
    int id = blockIdx.x;
    int res = id & 7;
    int q = id >> 3;
    int j_ = q % nyr;
    int mg = q / nyr;
    int mt = mg * 8 + res;
    const int MBcnt = (M + 127) >> 7;
    if (mt >= MBcnt) return;
    const int m0 = mt * 128;
    const int y = j_ % gy;
    const int r = j_ / gy;
    const int n0 = y * BN;

    const int tid = threadIdx.x;
    const int wv = tid >> 6;
    const int lane = tid & 63;

    __shared__ __align__(16) short lsA[3][4096];
    __shared__ __align__(16) short lsBh[3][BN * 32];

    const int wn0 = (wv >> 1) * (BN / 2);
    constexpr int JT = BN / 32;
    constexpr int NBL = BN / 64;
    constexpr int NL = 2 + NBL;

    floatx4 acc[4][JT];
#pragma unroll
    for (int i = 0; i < 4; i++)
#pragma unroll
        for (int j = 0; j < JT; j++) acc[i][j] = (floatx4)(0.f);

    const bf16* bh_r = Bh + (size_t)r * K * Nc;
    const int nkt = K >> 5;

    const bf16* aptr[2];
    short* adst[2];
#pragma unroll
    for (int c = 0; c < 2; c++) {
        int idx = c * 256 + tid;
        int half = idx >> 8;
        int it = (idx >> 6) & 3;
        int qq = (idx >> 4) & 3;
        int ml_ = idx & 15;
        int row = m0 + half * 64 + it * 16 + ml_;
        row = row < M ? row : M - 1;
        aptr[c] = A + (size_t)row * K + qq * 8;
        adst[c] = &lsA[0][(c * 256 + wv * 64) * 8];
    }
    const bf16* bhptr[NBL];
    short* bhdst[NBL];
#pragma unroll
    for (int c = 0; c < NBL; c++) {
        int idx = c * 256 + tid;
        int qq = idx / BN;
        int rem = idx % BN;
        int nt = rem >> 4;
        int nl = rem & 15;
        size_t goff = ((size_t)(qq * (Nc / 16) + (n0 >> 4) + nt) * 16 + nl) * 8;
        bhptr[c] = bh_r + goff;
        bhdst[c] = &lsBh[0][(c * 256 + wv * 64) * 8];
    }
    const size_t bstep = (size_t)32 * Nc;

#define STAGE_SM(BUF)                                                          \
    {                                                                          \
        _Pragma("unroll")                                                      \
        for (int c = 0; c < 2; c++) {                                          \
            async16(aptr[c], adst[c] + (BUF) * 4096);                          \
            aptr[c] += 32;                                                     \
        }                                                                      \
        _Pragma("unroll")                                                      \
        for (int c = 0; c < NBL; c++) {                                        \
            async16(bhptr[c], bhdst[c] + (BUF) * (BN * 32));                   \
            bhptr[c] += bstep;                                                 \
        }                                                                      \
    }

    STAGE_SM(0);
    STAGE_SM(1);

    int cur = 0;
    for (int kt = 0; kt < nkt; kt++) {
        if (kt + 1 < nkt) {
            asm volatile("s_waitcnt vmcnt(%0)" :: "n"(NL) : "memory");
        } else {
            asm volatile("s_waitcnt vmcnt(0)" ::: "memory");
        }
        __builtin_amdgcn_s_barrier();

        if (kt + 2 < nkt) {
            int stg = (cur == 0) ? 2 : cur - 1;
            STAGE_SM(stg);
        }

        short8 af[4];
#pragma unroll
        for (int i = 0; i < 4; i++)
            af[i] = *(const short8*)&lsA[cur][(((wv & 1) * 4 + i) * 64 + lane) * 8];

#pragma unroll
        for (int j = 0; j < JT; j++) {
            int ntl = (wv >> 1) * JT + j;
            int boff = ((lane >> 4) * BN + ntl * 16 + (lane & 15)) * 8;
            short8 bh = *(const short8*)&lsBh[cur][boff];
#pragma unroll
            for (int i = 0; i < 4; i++)
                acc[i][j] = __builtin_amdgcn_mfma_f32_16x16x32_bf16(af[i], bh, acc[i][j], 0, 0, 0);
        }
        cur = (cur == 2) ? 0 : cur + 1;
    }
#undef STAGE_SM

    const int ml = lane & 15, mq = lane >> 4;

    {
        bf16* rep = (bf16*)lsA;                  // 32 rows x BN cols
        constexpr int CPT = 8;
        constexpr int TPR = BN / CPT;
        constexpr int RPR = 256 / TPR;
        constexpr int NRND = 32 / RPR;
#pragma unroll
        for (int i = 0; i < 4; i++) {
            __syncthreads();
#pragma unroll
            for (int j = 0; j < JT; j++) {
                int col = wn0 + j * 16 + ml;
#pragma unroll
                for (int reg = 0; reg < 4; reg++) {
                    int rrow = (wv & 1) * 16 + mq * 4 + reg;
                    int blk = (col / CPT) ^ (((rrow >> 2) & 3) << 1);
                    rep[rrow * BN + blk * CPT + (col % CPT)] =
                        __float2bfloat16(acc[i][j][reg]);
                }
            }
            __syncthreads();
#pragma unroll
            for (int rr = 0; rr < NRND; rr++) {
                int lrow = rr * RPR + tid / TPR;
                int cblk = (tid % TPR) ^ (((lrow >> 2) & 3) << 1);
                uint4 v = *(const uint4*)&rep[lrow * BN + cblk * CPT];
                int m = m0 + (lrow >> 4) * 64 + i * 16 + (lrow & 15);
                if (m < M)
                    *(uint4*)&C[((size_t)m * NREL + r) * Nc + n0 + (tid % TPR) * CPT] = v;
            }
        }
    }
}

// ---------------------------------------------------------------------------
// Skinny dots GEMM: D[n, col] = x[n] . U[:, col]. RING-3, one barrier.
// ---------------------------------------------------------------------------
template <int KK, int HH>
__global__ __launch_bounds__(256) void dots_kernel(const bf16* __restrict__ A,
                                                   const bf16* __restrict__ Up,
                                                   float* __restrict__ sb,
                                                   float* __restrict__ db, int M) {
    constexpr int NCOL = NREL * 2 * HH;
    constexpr int JT = NCOL / 16;
    constexpr int nkt = KK / 32;
    constexpr int UCNT = KK * NCOL / 2048;

    const int m0 = blockIdx.x * 128;
    const int tid = threadIdx.x;
    const int wv = tid >> 6;
    const int lane = tid & 63;
    const int ml = lane & 15, mq = lane >> 4;

    __shared__ __align__(16) short smem[12288 + KK * NCOL];
    short* lsA = smem;            // [3][4096]
    short* lsU = smem + 12288;

#pragma unroll
    for (int c = 0; c < UCNT; c++)
        async16(Up + (size_t)(c * 256 + tid) * 8, lsU + (c * 256 + wv * 64) * 8);

    const bf16* aptr[2];
    int aoff[2];
#pragma unroll
    for (int c = 0; c < 2; c++) {
        int idx = c * 256 + tid;
        int half = idx >> 8;
        int it = (idx >> 6) & 3;
        int qq = (idx >> 4) & 3;
        int ml_ = idx & 15;
        int row = m0 + half * 64 + it * 16 + ml_;
        row = row < M ? row : M - 1;
        aptr[c] = A + (size_t)row * KK + qq * 8;
        aoff[c] = (c * 256 + wv * 64) * 8;
    }

    floatx4 acc[2][JT];
#pragma unroll
    for (int i = 0; i < 2; i++)
#pragma unroll
        for (int j = 0; j < JT; j++) acc[i][j] = (floatx4)(0.f);

#define STAGE_D(BUF)                                                           \
    {                                                                          \
        _Pragma("unroll")                                                      \
        for (int c = 0; c < 2; c++) {                                          \
            async16(aptr[c], lsA + (BUF) * 4096 + aoff[c]);                    \
            aptr[c] += 32;                                                     \
        }                                                                      \
    }

    STAGE_D(0);
    STAGE_D(1);

    int cur = 0;
    for (int kt = 0; kt < nkt; kt++) {
        if (kt + 1 < nkt) {
            asm volatile("s_waitcnt vmcnt(2)" ::: "memory");
        } else {
            asm volatile("s_waitcnt vmcnt(0)" ::: "memory");
        }
        __builtin_amdgcn_s_barrier();

        if (kt + 2 < nkt) {
            int stg = (cur == 0) ? 2 : cur - 1;
            STAGE_D(stg);
        }

        short8 af[2];
#pragma unroll
        for (int i = 0; i < 2; i++)
            af[i] = *(const short8*)&lsA[cur * 4096 + ((wv * 2 + i) * 64 + lane) * 8];

#pragma unroll
        for (int j = 0; j < JT; j++) {
            short8 bh = *(const short8*)&lsU[(((kt * 4 + mq) * JT + j) * 16 + ml) * 8];
#pragma unroll
            for (int i = 0; i < 2; i++)
                acc[i][j] = __builtin_amdgcn_mfma_f32_16x16x32_bf16(af[i], bh, acc[i][j], 0, 0, 0);
        }
        cur = (cur == 2) ? 0 : cur + 1;
    }
#undef STAGE_D

    float* Dst = (float*)smem;   // 128 x NCOL fp32
    __syncthreads();
#pragma unroll
    for (int i = 0; i < 2; i++) {
        int row = wv * 32 + i * 16 + mq * 4;
#pragma unroll
        for (int j = 0; j < JT; j++)
#pragma unroll
            for (int reg = 0; reg < 4; reg++)
                Dst[(row + reg) * NCOL + j * 16 + ml] = acc[i][j][reg];
    }
    __syncthreads();
    if constexpr (HH == 4) {
        int row = tid >> 1, half = tid & 1;
        int m = m0 + row;
        if (m < M) {
            float* tgt = half ? db : sb;
#pragma unroll
            for (int r = 0; r < 8; r++) {
                float4 v = *(float4*)&Dst[row * 64 + r * 8 + half * 4];
                *(float4*)&tgt[(size_t)m * 32 + r * 4] = v;
            }
        }
    } else {
        int row = tid & 127, half = tid >> 7;
        int m = m0 + row;
        if (m < M) {
            float* tgt = half ? db : sb;
#pragma unroll
            for (int r = 0; r < 8; r++)
                tgt[(size_t)m * 8 + r] = Dst[row * 16 + r * 2 + half];
        }
    }
}

// ---------------------------------------------------------------------------
// agg H=4, D=256 (bf16 xw). PERSISTENT: one wave strides over nodes; the
// measured-best round-1 gather body unchanged; node-invariant loads
// (ar, bias, gamma, beta) hoisted out of the node loop.
// ---------------------------------------------------------------------------
template <bool LNELU, typename OT>
__global__ __launch_bounds__(256) void agg_h4_kernel(
    const int* __restrict__ rowptr, const int* __restrict__ pks,
    const bf16* __restrict__ xw, const float* __restrict__ sb,
    const float* __restrict__ db, const float* __restrict__ ar,
    const float* __restrict__ bias, const float* __restrict__ gamma,
    const float* __restrict__ beta, OT* __restrict__ out, int N) {
    int wave = threadIdx.x >> 6;
    int lane = threadIdx.x & 63;
    int j4 = lane >> 2, hq = lane & 3;
    int g = lane & 31, p = lane >> 5;
    int c0 = g * 8, hd = g >> 3;

    float arv[8];
#pragma unroll
    for (int t = 0; t < 8; t++) arv[t] = ar[t * 4 + hq];
    float4 b0 = load4(bias + c0), b1 = load4(bias + c0 + 4);
    float gm[8], bt[8];
    if constexpr (LNELU) {
        float4 g0v = load4(gamma + c0), g1v = load4(gamma + c0 + 4);
        float4 be0v = load4(beta + c0), be1v = load4(beta + c0 + 4);
        gm[0] = g0v.x; gm[1] = g0v.y; gm[2] = g0v.z; gm[3] = g0v.w;
        gm[4] = g1v.x; gm[5] = g1v.y; gm[6] = g1v.z; gm[7] = g1v.w;
        bt[0] = be0v.x; bt[1] = be0v.y; bt[2] = be0v.z; bt[3] = be0v.w;
        bt[4] = be1v.x; bt[5] = be1v.y; bt[6] = be1v.z; bt[7] = be1v.w;
    }

    const int nw = gridDim.x * 4;
    for (int n = blockIdx.x * 4 + wave; n < N; n += nw) {
        int e0 = rowptr[n], e1 = rowptr[n + 1];
        int d = e1 - e0;

        float c8[8];
#pragma unroll
        for (int t = 0; t < 8; t++)
            c8[t] = db[((size_t)n * 8 + t) * 4 + hq] + arv[t];

        float acc[8] = {0.f, 0.f, 0.f, 0.f, 0.f, 0.f, 0.f, 0.f};
        float den = 0.f;

#define GATHER4(EBASE, EX, PK)                                                  \
    {                                                                           \
        int ea = (EBASE) + p, eb = ea + 2, ec = ea + 4, ed_ = ea + 6;           \
        float wa = __shfl(EX, (ea << 2) | hd, 64);                              \
        float wb = __shfl(EX, (eb << 2) | hd, 64);                              \
        float wc = __shfl(EX, (ec << 2) | hd, 64);                              \
        float wd = __shfl(EX, (ed_ << 2) | hd, 64);                             \
        int pa = __shfl(PK, ea << 2, 64);                                       \
        int pb = __shfl(PK, eb << 2, 64);                                       \
        int pc = __shfl(PK, ec << 2, 64);                                       \
        int pd_ = __shfl(PK, ed_ << 2, 64);                                     \
        uint4 ua = *(const uint4*)(xw + (size_t)pa * 256 + c0);                 \
        uint4 ub = *(const uint4*)(xw + (size_t)pb * 256 + c0);                 \
        uint4 uc = *(const uint4*)(xw + (size_t)pc * 256 + c0);                 \
        uint4 ud = *(const uint4*)(xw + (size_t)pd_ * 256 + c0);                \
        fma8(acc, wa, ua); fma8(acc, wb, ub); fma8(acc, wc, uc);                \
        fma8(acc, wd, ud);                                                      \
    }
#define GATHER1(S, EX, PK)                                                      \
    {                                                                           \
        int e = 2 * (S) + p;                                                    \
        float w = __shfl(EX, (e << 2) | hd, 64);                                \
        int pp = __shfl(PK, e << 2, 64);                                        \
        uint4 u = *(const uint4*)(xw + (size_t)pp * 256 + c0);                  \
        fma8(acc, w, u);                                                        \
    }

        for (int base = e0; base < e1; base += 16) {
            int e = base + j4;
            float ex = 0.f;
            int pk = 0;
            if (e < e1) {
                pk = pks[e];
                int t = pk & 7;
                float lg = sb[(size_t)pk * 4 + hq] + c8[t];
                lg = lg > 0.f ? lg : NEG_SLOPE * lg;
                ex = __expf(lg);
                den += ex;
            }
            int cnt = min(16, e1 - base);
            int steps = (cnt + 1) >> 1;
            int s = 0;
            for (; s + 4 <= steps; s += 4) GATHER4(2 * s, ex, pk);
            for (; s < steps; s++) GATHER1(s, ex, pk);
        }
#undef GATHER4
#undef GATHER1

#pragma unroll
        for (int off = 4; off < 64; off <<= 1) den += __shfl_xor(den, off, 64);
        float dv = __shfl(den, hd, 64);
        float deninv = d > 0 ? 1.f / dv : 0.f;

#pragma unroll
        for (int k = 0; k < 8; k++) acc[k] += __shfl_xor(acc[k], 32, 64);

        float o[8];
        o[0] = acc[0] * deninv + b0.x; o[1] = acc[1] * deninv + b0.y;
        o[2] = acc[2] * deninv + b0.z; o[3] = acc[3] * deninv + b0.w;
        o[4] = acc[4] * deninv + b1.x; o[5] = acc[5] * deninv + b1.y;
        o[6] = acc[6] * deninv + b1.z; o[7] = acc[7] * deninv + b1.w;

        if constexpr (LNELU) {
            float sum = 0.f, sq = 0.f;
#pragma unroll
            for (int k = 0; k < 8; k++) { sum += o[k]; sq += o[k] * o[k]; }
#pragma unroll
            for (int off = 1; off < 32; off <<= 1) {
                sum += __shfl_xor(sum, off, 64);
                sq  += __shfl_xor(sq, off, 64);
            }
            float mean = sum / 256.f;
            float var = sq / 256.f - mean * mean;
            float rstd = rsqrtf(var + LN_EPS);
#pragma unroll
            for (int k = 0; k < 8; k++) {
                float yv = gm[k] * (o[k] - mean) * rstd + bt[k];
                o[k] = yv > 0.f ? yv : expm1f(yv);
            }
        }

        if (p == 0) {
            if constexpr (sizeof(OT) == 2) {
                uint4 pkv;
                pkv.x = f2bu(o[0]) | (f2bu(o[1]) << 16);
                pkv.y = f2bu(o[2]) | (f2bu(o[3]) << 16);
                pkv.z = f2bu(o[4]) | (f2bu(o[5]) << 16);
                pkv.w = f2bu(o[6]) | (f2bu(o[7]) << 16);
                *(uint4*)&out[(size_t)n * 256 + c0] = pkv;
            } else {
                *(float4*)&out[(size_t)n * 256 + c0] = make_float4(o[0], o[1], o[2], o[3]);
                *(float4*)&out[(size_t)n * 256 + c0 + 4] = make_float4(o[4], o[5], o[6], o[7]);
            }
        }
    }
}

// ---------------------------------------------------------------------------
// agg H=1, D=64 (bf16 xw). PERSISTENT waves, round-1 body, hoisted constants.
// ---------------------------------------------------------------------------
__global__ __launch_bounds__(256) void agg_h1_kernel(
    const int* __restrict__ rowptr, const int* __restrict__ pks,
    const bf16* __restrict__ xw, const float* __restrict__ sb,
    const float* __restrict__ db, const float* __restrict__ ar,
    const float* __restrict__ bias, float* __restrict__ out, int N) {
    int wave = threadIdx.x >> 6;
    int lane = threadIdx.x & 63;
    int g = lane & 7, p = lane >> 3;
    int c0 = g * 8;

    float arv[8];
#pragma unroll
    for (int t = 0; t < 8; t++) arv[t] = ar[t];
    float4 b0 = load4(bias + c0), b1 = load4(bias + c0 + 4);

    const int nw = gridDim.x * 4;
    for (int n = blockIdx.x * 4 + wave; n < N; n += nw) {
        int e0 = rowptr[n], e1 = rowptr[n + 1];
        int d = e1 - e0;

        float c8[8];
#pragma unroll
        for (int t = 0; t < 8; t++) c8[t] = db[(size_t)n * 8 + t] + arv[t];

        float acc[8] = {0.f, 0.f, 0.f, 0.f, 0.f, 0.f, 0.f, 0.f};
        float den = 0.f;

#define GATH(S, EX, PK)                                                         \
    {                                                                           \
        int e = (S) * 8 + p;                                                    \
        float w = __shfl(EX, e, 64);                                            \
        int pp = __shfl(PK, e, 64);                                             \
        uint4 u = *(const uint4*)(xw + (size_t)pp * 64 + c0);                   \
        fma8(acc, w, u);                                                        \
    }

        for (int base = e0; base < e1; base += 64) {
            int e = base + lane;
            float ex = 0.f;
            int pk = 0;
            if (e < e1) {
                pk = pks[e];
                float lg = sb[pk] + c8[pk & 7];
                lg = lg > 0.f ? lg : NEG_SLOPE * lg;
                ex = __expf(lg);
                den += ex;
            }
            int cnt = min(64, e1 - base);
            int steps = (cnt + 7) >> 3;
            for (int s = 0; s < steps; s++) GATH(s, ex, pk);
        }
#undef GATH

#pragma unroll
        for (int off = 1; off < 64; off <<= 1) den += __shfl_xor(den, off, 64);
        float deninv = d > 0 ? 1.f / den : 0.f;

#pragma unroll
        for (int k = 0; k < 8; k++) {
            acc[k] += __shfl_xor(acc[k], 8, 64);
            acc[k] += __shfl_xor(acc[k], 16, 64);
            acc[k] += __shfl_xor(acc[k], 32, 64);
        }
        if (p == 0) {
            *(float4*)&out[(size_t)n * 64 + c0] =
                make_float4(acc[0] * deninv + b0.x, acc[1] * deninv + b0.y,
                            acc[2] * deninv + b0.z, acc[3] * deninv + b0.w);
            *(float4*)&out[(size_t)n * 64 + c0 + 4] =
                make_float4(acc[4] * deninv + b1.x, acc[5] * deninv + b1.y,
                            acc[6] * deninv + b1.z, acc[7] * deninv + b1.w);
        }
    }
}

// ---------------------------------------------------------------------------
extern "C" void kernel_launch(void* const* d_in, const int* in_sizes, int n_in,
                              void* d_out, int out_size, void* d_ws, size_t ws_size,
                              hipStream_t stream) {
    const float* x   = (const float*)d_in[0];
    const int* eidx  = (const int*)d_in[1];
    const int* etyp  = (const int*)d_in[2];
    const float* W0  = (const float*)d_in[3];
    const float* as0 = (const float*)d_in[4];
    const float* ad0 = (const float*)d_in[5];
    const float* ar0 = (const float*)d_in[6];
    const float* bi0 = (const float*)d_in[7];
    const float* W1  = (const float*)d_in[8];
    const float* as1 = (const float*)d_in[9];
    const float* ad1 = (const float*)d_in[10];
    const float* ar1 = (const float*)d_in[11];
    const float* bi1 = (const float*)d_in[12];
    const float* W2  = (const float*)d_in[13];
    const float* as2 = (const float*)d_in[14];
    const float* ad2 = (const float*)d_in[15];
    const float* ar2 = (const float*)d_in[16];
    const float* bi2 = (const float*)d_in[17];
    const float* g0  = (const float*)d_in[18];
    const float* be0 = (const float*)d_in[19];
    const float* g1  = (const float*)d_in[20];
    const float* be1 = (const float*)d_in[21];

    const int E = in_sizes[2];
    const int N = in_sizes[0] / 128;

    size_t off = 0;
    char* wsb = (char*)d_ws;
    auto alloc = [&](size_t bytes) -> void* {
        void* p = wsb + off;
        off += (bytes + 255) & ~(size_t)255;
        return p;
    };
    bf16* xw = (bf16*)alloc((size_t)N * NREL * 256 * sizeof(bf16));  // 204.8 MB
    char* h_region = (char*)alloc((size_t)N * 256 * sizeof(bf16));
    bf16* h  = (bf16*)h_region;
    bf16* xb = (bf16*)h_region;      // x bf16 aliases h (dead before h written)
    float* sb   = (float*)alloc((size_t)N * NREL * 4 * sizeof(float));
    float* db   = (float*)alloc((size_t)N * NREL * 4 * sizeof(float));
    int* cnt    = (int*)alloc((size_t)N * sizeof(int));
    int* rowptr = (int*)alloc((size_t)(N + 1) * sizeof(int));
    int* bsum   = (int*)alloc(64 * sizeof(int));
    int* pks    = (int*)alloc((size_t)E * sizeof(int));
    const int szW0 = NREL * 128 * 256, szW1 = NREL * 256 * 256, szW2 = NREL * 256 * 64;
    bf16* Wh0 = (bf16*)alloc((size_t)szW0 * sizeof(bf16));
    bf16* Wh1 = (bf16*)alloc((size_t)szW1 * sizeof(bf16));
    bf16* Wh2 = (bf16*)alloc((size_t)szW2 * sizeof(bf16));
    bf16* Up0 = (bf16*)alloc((size_t)128 * 64 * sizeof(bf16));
    bf16* Up1 = (bf16*)alloc((size_t)256 * 64 * sizeof(bf16));
    bf16* Up2 = (bf16*)alloc((size_t)256 * 16 * sizeof(bf16));

    const int* srcs = eidx;
    const int* dsts = eidx + E;

    convx_kernel<<<(N * 128 / 4 + 255) / 256, 256, 0, stream>>>(x, xb, N * 128 / 4);
    packw_kernel<<<(szW0 + 255) / 256, 256, 0, stream>>>(W0, Wh0, 128, 256, szW0);
    packw_kernel<<<(szW1 + 255) / 256, 256, 0, stream>>>(W1, Wh1, 256, 256, szW1);
    packw_kernel<<<(szW2 + 255) / 256, 256, 0, stream>>>(W2, Wh2, 256, 64, szW2);
    prepu_kernel<4><<<32, 256, 0, stream>>>(W0, as0, ad0, Up0, 128);
    prepu_kernel<4><<<64, 256, 0, stream>>>(W1, as1, ad1, Up1, 256);
    prepu_kernel<1><<<16, 256, 0, stream>>>(W2, as2, ad2, Up2, 256);

    const int NB = (N + 1023) / 1024;
    hipMemsetAsync(cnt, 0, N * sizeof(int), stream);
    count_kernel<<<(E + 255) / 256, 256, 0, stream>>>(dsts, cnt, E);
    scan1_kernel<<<NB, 1024, 0, stream>>>(cnt, rowptr, bsum, N);
    scan2_kernel<<<1, 64, 0, stream>>>(bsum, NB);
    scan3_kernel<<<NB, 1024, 0, stream>>>(rowptr, bsum, N);
    hipMemsetAsync(cnt, 0, N * sizeof(int), stream);
    fill_kernel<<<(E + 255) / 256, 256, 0, stream>>>(srcs, dsts, etyp, rowptr, cnt, pks, E);

    const int MB = (N + 127) / 128;
    const int MBp = ((MB + 7) / 8) * 8;
    const int MB2 = (N + 255) / 256;
    const int MBp2 = ((MB2 + 7) / 8) * 8;
    const int DB = MB;
    const int AGGB = 2048;   // persistent: ~8 blocks/CU worth

    // layer 0: in=128 -> D=256, heads=4, LN+ELU
    mfma_gemm_big<<<dim3(MBp2 * 2 * NREL), 512, 0, stream>>>(xb, Wh0, xw, N, 128, 256);
    dots_kernel<128, 4><<<DB, 256, 0, stream>>>(xb, Up0, sb, db, N);
    agg_h4_kernel<true, bf16><<<AGGB, 256, 0, stream>>>(
        rowptr, pks, xw, sb, db, ar0, bi0, g0, be0, h, N);

    // layer 1: in=256 -> D=256, heads=4, LN+ELU
    mfma_gemm_big<<<dim3(MBp2 * 2 * NREL), 512, 0, stream>>>(h, Wh1, xw, N, 256, 256);
    dots_kernel<256, 4><<<DB, 256, 0, stream>>>(h, Up1, sb, db, N);
    agg_h4_kernel<true, bf16><<<AGGB, 256, 0, stream>>>(
        rowptr, pks, xw, sb, db, ar1, bi1, g1, be1, h, N);

    // layer 2: in=256 -> D=64, heads=1, bf16 xw, fp32 output
    mfma_gemm<64><<<dim3(MBp * 1 * NREL), 256, 0, stream>>>(h, Wh2, xw, N, 256, 64);
    dots_kernel<256, 1><<<DB, 256, 0, stream>>>(h, Up2, sb, db, N);
    agg_h1_kernel<<<AGGB, 256, 0, stream>>>(
        rowptr, pks, xw, sb, db, ar2, bi2, (float*)d_out, N);
}

// Round 6
// 606.746 us; speedup vs baseline: 1.0373x; 1.0373x over previous
//
#include <hip/hip_runtime.h>
#include <hip/hip_bf16.h>
#include <math.h>

#define NREL 8
#define LN_EPS 1e-5f
#define NEG_SLOPE 0.2f

typedef __hip_bfloat16 bf16;
typedef __attribute__((ext_vector_type(8))) short short8;
typedef __attribute__((ext_vector_type(4))) float floatx4;

__device__ __forceinline__ unsigned int f2bu(float v) {
    bf16 t = __float2bfloat16(v);
    return (unsigned int)*reinterpret_cast<unsigned short*>(&t);
}

__device__ __forceinline__ float4 load4(const float* p) { return *(const float4*)p; }

__device__ __forceinline__ void fma8(float acc[8], float w, uint4 u) {
    union { unsigned int i; float f; } t;
    t.i = u.x << 16;          acc[0] = fmaf(w, t.f, acc[0]);
    t.i = u.x & 0xffff0000u;  acc[1] = fmaf(w, t.f, acc[1]);
    t.i = u.y << 16;          acc[2] = fmaf(w, t.f, acc[2]);
    t.i = u.y & 0xffff0000u;  acc[3] = fmaf(w, t.f, acc[3]);
    t.i = u.z << 16;          acc[4] = fmaf(w, t.f, acc[4]);
    t.i = u.z & 0xffff0000u;  acc[5] = fmaf(w, t.f, acc[5]);
    t.i = u.w << 16;          acc[6] = fmaf(w, t.f, acc[6]);
    t.i = u.w & 0xffff0000u;  acc[7] = fmaf(w, t.f, acc[7]);
}

__device__ __forceinline__ void async16(const void* g, void* l) {
    __builtin_amdgcn_global_load_lds(
        (const __attribute__((address_space(1))) void*)g,
        (__attribute__((address_space(3))) void*)l, 16, 0, 0);
}

// ---------------------------------------------------------------------------
// CSR build: count -> hierarchical scan -> fill.
// pk = (rowidx<<3)|rel, rowidx = rel*N + src  (matches r-major xw layout).
// ---------------------------------------------------------------------------
__global__ __launch_bounds__(256) void count_kernel(const int* __restrict__ dst,
                                                    int* __restrict__ cnt, int E) {
    int e = blockIdx.x * 256 + threadIdx.x;
    if (e < E) atomicAdd(&cnt[dst[e]], 1);
}

__global__ __launch_bounds__(1024) void scan1_kernel(const int* __restrict__ cnt,
                                                     int* __restrict__ rowptr,
                                                     int* __restrict__ bsum, int N) {
    __shared__ int sm[1024];
    int tid = threadIdx.x;
    int base = blockIdx.x * 1024;
    int v = (base + tid < N) ? cnt[base + tid] : 0;
    sm[tid] = v;
    __syncthreads();
    for (int off = 1; off < 1024; off <<= 1) {
        int t = (tid >= off) ? sm[tid - off] : 0;
        __syncthreads();
        sm[tid] += t;
        __syncthreads();
    }
    if (base + tid < N) rowptr[base + tid + 1] = sm[tid];
    if (tid == 1023) bsum[blockIdx.x] = sm[1023];
    if (blockIdx.x == 0 && tid == 0) rowptr[0] = 0;
}

__global__ __launch_bounds__(64) void scan2_kernel(int* __restrict__ bsum, int nb) {
    int lane = threadIdx.x;
    int v = (lane < nb) ? bsum[lane] : 0;
    for (int off = 1; off < 64; off <<= 1) {
        int t = __shfl_up(v, off, 64);
        if (lane >= off) v += t;
    }
    int ex = __shfl_up(v, 1, 64);
    if (lane == 0) ex = 0;
    if (lane < nb) bsum[lane] = ex;
}

__global__ __launch_bounds__(1024) void scan3_kernel(int* __restrict__ rowptr,
                                                     const int* __restrict__ bsum, int N) {
    int i = blockIdx.x * 1024 + threadIdx.x;
    if (i < N) rowptr[i + 1] += bsum[blockIdx.x];
}

__global__ __launch_bounds__(256) void fill_kernel(const int* __restrict__ src,
                                                   const int* __restrict__ dst,
                                                   const int* __restrict__ et,
                                                   const int* __restrict__ rowptr,
                                                   int* __restrict__ cursor,
                                                   int* __restrict__ pks, int E, int N) {
    int e = blockIdx.x * 256 + threadIdx.x;
    if (e < E) {
        int d = dst[e];
        int t = et[e];
        int pos = atomicAdd(&cursor[d], 1);
        pks[rowptr[d] + pos] = ((t * N + src[e]) << 3) | t;
    }
}

// ---------------------------------------------------------------------------
// x fp32 -> bf16 (vectorized)
// ---------------------------------------------------------------------------
__global__ __launch_bounds__(256) void convx_kernel(const float* __restrict__ x,
                                                    bf16* __restrict__ xb, int total4) {
    int i = blockIdx.x * 256 + threadIdx.x;
    if (i < total4) {
        float4 v = ((const float4*)x)[i];
        ushort4 o;
        o.x = (unsigned short)f2bu(v.x);
        o.y = (unsigned short)f2bu(v.y);
        o.z = (unsigned short)f2bu(v.z);
        o.w = (unsigned short)f2bu(v.w);
        ((ushort4*)xb)[i] = o;
    }
}

// ---------------------------------------------------------------------------
// Pack W fp32 [R][K][Nc] into MFMA-B-fragment order (hi bf16 only).
// ---------------------------------------------------------------------------
__global__ __launch_bounds__(256) void packw_kernel(const float* __restrict__ W,
                                                    bf16* __restrict__ hi,
                                                    int K, int Nc, int total) {
    int i = blockIdx.x * 256 + threadIdx.x;
    if (i >= total) return;
    int kk = i & 7;
    int t1 = i >> 3;
    int nl = t1 & 15;
    int t2 = t1 >> 4;
    int nt = t2 % (Nc / 16);
    int t3 = t2 / (Nc / 16);
    int q = t3 & 3;
    int t4 = t3 >> 2;
    int kt = t4 % (K / 32);
    int r = t4 / (K / 32);
    int k = kt * 32 + q * 8 + kk;
    int n = nt * 16 + nl;
    hi[i] = __float2bfloat16(W[((size_t)r * K + k) * Nc + n]);
}

// ---------------------------------------------------------------------------
// Precompute U[k][col] = sum_c W[r][k][h*64+c] * a_{sd}[h][c], packed in MFMA
// B-fragment order (col = r*2H + sd*H + h).
// ---------------------------------------------------------------------------
template <int HH>
__global__ __launch_bounds__(256) void prepu_kernel(const float* __restrict__ W,
                                                    const float* __restrict__ as_,
                                                    const float* __restrict__ ad_,
                                                    bf16* __restrict__ Up, int K) {
    constexpr int NCOL = NREL * 2 * HH;
    constexpr int JT = NCOL / 16;
    int idx = blockIdx.x * 256 + threadIdx.x;
    if (idx >= K * NCOL) return;
    int kk = idx & 7;
    int t1 = idx >> 3;
    int nl = t1 & 15;
    int t2 = t1 >> 4;
    int nt = t2 % JT;
    int t3 = t2 / JT;
    int q = t3 & 3;
    int kt = t3 >> 2;
    int k = kt * 32 + q * 8 + kk;
    int col = nt * 16 + nl;
    int r = col / (2 * HH);
    int rem = col % (2 * HH);
    int sd = rem / HH;
    int h = rem % HH;
    const float* a = (sd ? ad_ : as_) + h * 64;
    const float* w = W + ((size_t)r * K + k) * (HH * 64) + h * 64;
    float s = 0.f;
#pragma unroll
    for (int c = 0; c < 16; c++) {
        float4 wv4 = load4(w + c * 4);
        float4 av4 = load4(a + c * 4);
        s += wv4.x * av4.x + wv4.y * av4.y + wv4.z * av4.z + wv4.w * av4.w;
    }
    Up[idx] = __float2bfloat16(s);
}

// ---------------------------------------------------------------------------
// Big MFMA GEMM: 256x128 tile, 8 waves (4m x 2n), RING-3, one barrier/K-step.
// C layout is RELATION-MAJOR: C[(r*M + m)*Nc + col]. For fixed r this makes
// each store round a dense 16KB-contiguous span (rows 512B apart, fully
// covered) instead of 256B granules at 4KB stride -- the write-page-locality
// cap that pinned all prior schedules at ~2.1 TB/s.
// ---------------------------------------------------------------------------
__global__ __launch_bounds__(512) void mfma_gemm_big(const bf16* __restrict__ A,
                                                     const bf16* __restrict__ Bh,
                                                     bf16* __restrict__ C,
                                                     int M, int K, int Nc) {
    const int gy = Nc / 128;          // 2
    const int nyr = gy * NREL;        // 16
    int id = blockIdx.x;
    int res = id & 7;
    int q = id >> 3;
    int j_ = q % nyr;
    int mg = q / nyr;
    int mt = mg * 8 + res;
    const int MBcnt = (M + 255) >> 8;
    if (mt >= MBcnt) return;
    const int m0 = mt * 256;
    const int y = j_ % gy;
    const int r = j_ / gy;
    const int n0 = y * 128;

    const int tid = threadIdx.x;
    const int wv = tid >> 6;
    const int lane = tid & 63;
    const int wm = wv & 3, wn = wv >> 2;
    const int ml = lane & 15, mq = lane >> 4;

    __shared__ __align__(16) short lsA[3][8192];    // 3 x 16KB A tiles
    __shared__ __align__(16) short lsBh[3][4096];   // 3 x 8KB B tiles

    floatx4 acc[4][4];
#pragma unroll
    for (int i = 0; i < 4; i++)
#pragma unroll
        for (int j = 0; j < 4; j++) acc[i][j] = (floatx4)(0.f);

    const int nkt = K >> 5;

    // A staging: 1024 slots (16KB), 2 per thread. slot = rgrp*256+it*64+qq*16+ml_
    const bf16* aptr[2];
    short* adst[2];
#pragma unroll
    for (int c = 0; c < 2; c++) {
        int idx = c * 512 + tid;
        int rgrp = idx >> 8;
        int it = (idx >> 6) & 3;
        int qq = (idx >> 4) & 3;
        int ml_ = idx & 15;
        int row = m0 + rgrp * 64 + it * 16 + ml_;
        row = row < M ? row : M - 1;
        aptr[c] = A + (size_t)row * K + qq * 8;
        adst[c] = &lsA[0][(c * 512 + wv * 64) * 8];
    }
    // B staging: 512 slots (8KB), 1 per thread. slot = qq*128 + nt*16 + nl
    const bf16* bptr;
    short* bdst;
    {
        int qq = tid >> 7;
        int rem = tid & 127;
        int nt = rem >> 4;
        int nl = rem & 15;
        bptr = Bh + (size_t)r * K * Nc +
               ((size_t)(qq * (Nc / 16) + (n0 >> 4) + nt) * 16 + nl) * 8;
        bdst = &lsBh[0][(wv * 64) * 8];
    }
    const size_t bstep = (size_t)32 * Nc;

#define STAGE_BIG(BUF)                                                         \
    {                                                                          \
        _Pragma("unroll")                                                      \
        for (int c = 0; c < 2; c++) {                                          \
            async16(aptr[c], adst[c] + (BUF) * 8192);                          \
            aptr[c] += 32;                                                     \
        }                                                                      \
        async16(bptr, bdst + (BUF) * 4096);                                    \
        bptr += bstep;                                                         \
    }

    // prologue: tiles 0,1 into buffers 0,1
    STAGE_BIG(0);
    STAGE_BIG(1);

    int cur = 0;
    for (int kt = 0; kt < nkt; kt++) {
        if (kt + 1 < nkt) {
            asm volatile("s_waitcnt vmcnt(3)" ::: "memory");
        } else {
            asm volatile("s_waitcnt vmcnt(0)" ::: "memory");
        }
        __builtin_amdgcn_s_barrier();

        if (kt + 2 < nkt) {
            int stg = (cur == 0) ? 2 : cur - 1;   // (cur+2)%3
            STAGE_BIG(stg);
        }

        short8 af[4];
#pragma unroll
        for (int i = 0; i < 4; i++)
            af[i] = *(const short8*)&lsA[cur][(wm * 256 + i * 64 + lane) * 8];

#pragma unroll
        for (int j = 0; j < 4; j++) {
            int ntl = wn * 4 + j;
            short8 bh = *(const short8*)&lsBh[cur][(mq * 128 + ntl * 16 + ml) * 8];
#pragma unroll
            for (int i = 0; i < 4; i++)
                acc[i][j] = __builtin_amdgcn_mfma_f32_16x16x32_bf16(af[i], bh, acc[i][j], 0, 0, 0);
        }
        cur = (cur == 2) ? 0 : cur + 1;
    }
#undef STAGE_BIG

    // ---- C store via XOR-swizzled LDS repack, r-major cached stores ----
    {
        bf16* rep = (bf16*)lsA;                  // 64 x 128 bf16 = 16KB
#pragma unroll
        for (int i = 0; i < 4; i++) {
            __syncthreads();
#pragma unroll
            for (int j = 0; j < 4; j++) {
                int col = wn * 64 + j * 16 + ml;
#pragma unroll
                for (int reg = 0; reg < 4; reg++) {
                    int rrow = wm * 16 + mq * 4 + reg;
                    int blk = (col >> 3) ^ (((rrow >> 2) & 3) << 1);
                    rep[rrow * 128 + blk * 8 + (col & 7)] =
                        __float2bfloat16(acc[i][j][reg]);
                }
            }
            __syncthreads();
#pragma unroll
            for (int rr = 0; rr < 2; rr++) {
                int lrow = rr * 32 + (tid >> 4);
                int cblk = (tid & 15) ^ (((lrow >> 2) & 3) << 1);
                uint4 v = *(const uint4*)&rep[lrow * 128 + cblk * 8];
                int m = m0 + (lrow >> 4) * 64 + i * 16 + (lrow & 15);
                if (m < M)
                    *(uint4*)&C[((size_t)r * M + m) * Nc + n0 + (tid & 15) * 8] = v;
            }
        }
    }
}

// ---------------------------------------------------------------------------
// MFMA GEMM (128-tile, 4 waves) — layer-2 GEMM (BN=64). RING-3, one barrier.
// r-major C layout.
// ---------------------------------------------------------------------------
template <int BN>
__global__ __launch_bounds__(256) void mfma_gemm(const bf16* __restrict__ A,
                                                 const bf16* __restrict__ Bh,
                                                 bf16* __restrict__ C,
                                                 int M, int K, int Nc) {
    const int gy = Nc / BN;
    const int nyr = gy * NREL;
    int id = blockIdx.x;
    int res = id & 7;
    int q = id >> 3;
    int j_ = q % nyr;
    int mg = q / nyr;
    int mt = mg * 8 + res;
    const int MBcnt = (M + 127) >> 7;
    if (mt >= MBcnt) return;
    const int m0 = mt * 128;
    const int y = j_ % gy;
    const int r = j_ / gy;
    const int n0 = y * BN;

    const int tid = threadIdx.x;
    const int wv = tid >> 6;
    const int lane = tid & 63;

    __shared__ __align__(16) short lsA[3][4096];
    __shared__ __align__(16) short lsBh[3][BN * 32];

    const int wn0 = (wv >> 1) * (BN / 2);
    constexpr int JT = BN / 32;
    constexpr int NBL = BN / 64;
    constexpr int NL = 2 + NBL;

    floatx4 acc[4][JT];
#pragma unroll
    for (int i = 0; i < 4; i++)
#pragma unroll
        for (int j = 0; j < JT; j++) acc[i][j] = (floatx4)(0.f);

    const bf16* bh_r = Bh + (size_t)r * K * Nc;
    const int nkt = K >> 5;

    const bf16* aptr[2];
    short* adst[2];
#pragma unroll
    for (int c = 0; c < 2; c++) {
        int idx = c * 256 + tid;
        int half = idx >> 8;
        int it = (idx >> 6) & 3;
        int qq = (idx >> 4) & 3;
        int ml_ = idx & 15;
        int row = m0 + half * 64 + it * 16 + ml_;
        row = row < M ? row : M - 1;
        aptr[c] = A + (size_t)row * K + qq * 8;
        adst[c] = &lsA[0][(c * 256 + wv * 64) * 8];
    }
    const bf16* bhptr[NBL];
    short* bhdst[NBL];
#pragma unroll
    for (int c = 0; c < NBL; c++) {
        int idx = c * 256 + tid;
        int qq = idx / BN;
        int rem = idx % BN;
        int nt = rem >> 4;
        int nl = rem & 15;
        size_t goff = ((size_t)(qq * (Nc / 16) + (n0 >> 4) + nt) * 16 + nl) * 8;
        bhptr[c] = bh_r + goff;
        bhdst[c] = &lsBh[0][(c * 256 + wv * 64) * 8];
    }
    const size_t bstep = (size_t)32 * Nc;

#define STAGE_SM(BUF)                                                          \
    {                                                                          \
        _Pragma("unroll")                                                      \
        for (int c = 0; c < 2; c++) {                                          \
            async16(aptr[c], adst[c] + (BUF) * 4096);                          \
            aptr[c] += 32;                                                     \
        }                                                                      \
        _Pragma("unroll")                                                      \
        for (int c = 0; c < NBL; c++) {                                        \
            async16(bhptr[c], bhdst[c] + (BUF) * (BN * 32));                   \
            bhptr[c] += bstep;                                                 \
        }                                                                      \
    }

    STAGE_SM(0);
    STAGE_SM(1);

    int cur = 0;
    for (int kt = 0; kt < nkt; kt++) {
        if (kt + 1 < nkt) {
            asm volatile("s_waitcnt vmcnt(%0)" :: "n"(NL) : "memory");
        } else {
            asm volatile("s_waitcnt vmcnt(0)" ::: "memory");
        }
        __builtin_amdgcn_s_barrier();

        if (kt + 2 < nkt) {
            int stg = (cur == 0) ? 2 : cur - 1;
            STAGE_SM(stg);
        }

        short8 af[4];
#pragma unroll
        for (int i = 0; i < 4; i++)
            af[i] = *(const short8*)&lsA[cur][(((wv & 1) * 4 + i) * 64 + lane) * 8];

#pragma unroll
        for (int j = 0; j < JT; j++) {
            int ntl = (wv >> 1) * JT + j;
            int boff = ((lane >> 4) * BN + ntl * 16 + (lane & 15)) * 8;
            short8 bh = *(const short8*)&lsBh[cur][boff];
#pragma unroll
            for (int i = 0; i < 4; i++)
                acc[i][j] = __builtin_amdgcn_mfma_f32_16x16x32_bf16(af[i], bh, acc[i][j], 0, 0, 0);
        }
        cur = (cur == 2) ? 0 : cur + 1;
    }
#undef STAGE_SM

    const int ml = lane & 15, mq = lane >> 4;

    {
        bf16* rep = (bf16*)lsA;                  // 32 rows x BN cols
        constexpr int CPT = 8;
        constexpr int TPR = BN / CPT;
        constexpr int RPR = 256 / TPR;
        constexpr int NRND = 32 / RPR;
#pragma unroll
        for (int i = 0; i < 4; i++) {
            __syncthreads();
#pragma unroll
            for (int j = 0; j < JT; j++) {
                int col = wn0 + j * 16 + ml;
#pragma unroll
                for (int reg = 0; reg < 4; reg++) {
                    int rrow = (wv & 1) * 16 + mq * 4 + reg;
                    int blk = (col / CPT) ^ (((rrow >> 2) & 3) << 1);
                    rep[rrow * BN + blk * CPT + (col % CPT)] =
                        __float2bfloat16(acc[i][j][reg]);
                }
            }
            __syncthreads();
#pragma unroll
            for (int rr = 0; rr < NRND; rr++) {
                int lrow = rr * RPR + tid / TPR;
                int cblk = (tid % TPR) ^ (((lrow >> 2) & 3) << 1);
                uint4 v = *(const uint4*)&rep[lrow * BN + cblk * CPT];
                int m = m0 + (lrow >> 4) * 64 + i * 16 + (lrow & 15);
                if (m < M)
                    *(uint4*)&C[((size_t)r * M + m) * Nc + n0 + (tid % TPR) * CPT] = v;
            }
        }
    }
}

// ---------------------------------------------------------------------------
// Skinny dots GEMM: D[n, col] = x[n] . U[:, col]. RING-3, one barrier.
// sb written in r-major layout sb[(r*N + m)*HH + h]; db stays node-major.
// ---------------------------------------------------------------------------
template <int KK, int HH>
__global__ __launch_bounds__(256) void dots_kernel(const bf16* __restrict__ A,
                                                   const bf16* __restrict__ Up,
                                                   float* __restrict__ sb,
                                                   float* __restrict__ db, int M) {
    constexpr int NCOL = NREL * 2 * HH;
    constexpr int JT = NCOL / 16;
    constexpr int nkt = KK / 32;
    constexpr int UCNT = KK * NCOL / 2048;

    const int m0 = blockIdx.x * 128;
    const int tid = threadIdx.x;
    const int wv = tid >> 6;
    const int lane = tid & 63;
    const int ml = lane & 15, mq = lane >> 4;

    __shared__ __align__(16) short smem[12288 + KK * NCOL];
    short* lsA = smem;            // [3][4096]
    short* lsU = smem + 12288;

#pragma unroll
    for (int c = 0; c < UCNT; c++)
        async16(Up + (size_t)(c * 256 + tid) * 8, lsU + (c * 256 + wv * 64) * 8);

    const bf16* aptr[2];
    int aoff[2];
#pragma unroll
    for (int c = 0; c < 2; c++) {
        int idx = c * 256 + tid;
        int half = idx >> 8;
        int it = (idx >> 6) & 3;
        int qq = (idx >> 4) & 3;
        int ml_ = idx & 15;
        int row = m0 + half * 64 + it * 16 + ml_;
        row = row < M ? row : M - 1;
        aptr[c] = A + (size_t)row * KK + qq * 8;
        aoff[c] = (c * 256 + wv * 64) * 8;
    }

    floatx4 acc[2][JT];
#pragma unroll
    for (int i = 0; i < 2; i++)
#pragma unroll
        for (int j = 0; j < JT; j++) acc[i][j] = (floatx4)(0.f);

#define STAGE_D(BUF)                                                           \
    {                                                                          \
        _Pragma("unroll")                                                      \
        for (int c = 0; c < 2; c++) {                                          \
            async16(aptr[c], lsA + (BUF) * 4096 + aoff[c]);                    \
            aptr[c] += 32;                                                     \
        }                                                                      \
    }

    STAGE_D(0);
    STAGE_D(1);

    int cur = 0;
    for (int kt = 0; kt < nkt; kt++) {
        if (kt + 1 < nkt) {
            asm volatile("s_waitcnt vmcnt(2)" ::: "memory");
        } else {
            asm volatile("s_waitcnt vmcnt(0)" ::: "memory");
        }
        __builtin_amdgcn_s_barrier();

        if (kt + 2 < nkt) {
            int stg = (cur == 0) ? 2 : cur - 1;
            STAGE_D(stg);
        }

        short8 af[2];
#pragma unroll
        for (int i = 0; i < 2; i++)
            af[i] = *(const short8*)&lsA[cur * 4096 + ((wv * 2 + i) * 64 + lane) * 8];

#pragma unroll
        for (int j = 0; j < JT; j++) {
            short8 bh = *(const short8*)&lsU[(((kt * 4 + mq) * JT + j) * 16 + ml) * 8];
#pragma unroll
            for (int i = 0; i < 2; i++)
                acc[i][j] = __builtin_amdgcn_mfma_f32_16x16x32_bf16(af[i], bh, acc[i][j], 0, 0, 0);
        }
        cur = (cur == 2) ? 0 : cur + 1;
    }
#undef STAGE_D

    float* Dst = (float*)smem;   // 128 x NCOL fp32
    __syncthreads();
#pragma unroll
    for (int i = 0; i < 2; i++) {
        int row = wv * 32 + i * 16 + mq * 4;
#pragma unroll
        for (int j = 0; j < JT; j++)
#pragma unroll
            for (int reg = 0; reg < 4; reg++)
                Dst[(row + reg) * NCOL + j * 16 + ml] = acc[i][j][reg];
    }
    __syncthreads();
    if constexpr (HH == 4) {
        int row = tid >> 1, half = tid & 1;
        int m = m0 + row;
        if (m < M) {
            if (half) {
#pragma unroll
                for (int r = 0; r < 8; r++) {
                    float4 v = *(float4*)&Dst[row * 64 + r * 8 + 4];
                    *(float4*)&db[(size_t)m * 32 + r * 4] = v;
                }
            } else {
#pragma unroll
                for (int r = 0; r < 8; r++) {
                    float4 v = *(float4*)&Dst[row * 64 + r * 8];
                    *(float4*)&sb[((size_t)r * M + m) * 4] = v;
                }
            }
        }
    } else {
        int row = tid & 127, half = tid >> 7;
        int m = m0 + row;
        if (m < M) {
            if (half) {
#pragma unroll
                for (int r = 0; r < 8; r++)
                    db[(size_t)m * 8 + r] = Dst[row * 16 + r * 2 + 1];
            } else {
#pragma unroll
                for (int r = 0; r < 8; r++)
                    sb[(size_t)r * M + m] = Dst[row * 16 + r * 2];
            }
        }
    }
}

// ---------------------------------------------------------------------------
// agg H=4, D=256 (bf16 xw, r-major rows via pk>>3). One wave per node.
// (round-1 measured-best gather body)
// ---------------------------------------------------------------------------
template <bool LNELU, typename OT>
__global__ __launch_bounds__(256) void agg_h4_kernel(
    const int* __restrict__ rowptr, const int* __restrict__ pks,
    const bf16* __restrict__ xw, const float* __restrict__ sb,
    const float* __restrict__ db, const float* __restrict__ ar,
    const float* __restrict__ bias, const float* __restrict__ gamma,
    const float* __restrict__ beta, OT* __restrict__ out, int N) {
    int wave = threadIdx.x >> 6;
    int lane = threadIdx.x & 63;
    int n = blockIdx.x * 4 + wave;
    if (n >= N) return;
    int e0 = rowptr[n], e1 = rowptr[n + 1];
    int d = e1 - e0;
    int j4 = lane >> 2, hq = lane & 3;
    int g = lane & 31, p = lane >> 5;
    int c0 = g * 8, hd = g >> 3;

    float c8[8];
#pragma unroll
    for (int t = 0; t < 8; t++)
        c8[t] = db[((size_t)n * 8 + t) * 4 + hq] + ar[t * 4 + hq];

    float acc[8] = {0.f, 0.f, 0.f, 0.f, 0.f, 0.f, 0.f, 0.f};
    float den = 0.f;

#define GATHER4(EBASE, EX, PK)                                                  \
    {                                                                           \
        int ea = (EBASE) + p, eb = ea + 2, ec = ea + 4, ed_ = ea + 6;           \
        float wa = __shfl(EX, (ea << 2) | hd, 64);                              \
        float wb = __shfl(EX, (eb << 2) | hd, 64);                              \
        float wc = __shfl(EX, (ec << 2) | hd, 64);                              \
        float wd = __shfl(EX, (ed_ << 2) | hd, 64);                             \
        int pa = __shfl(PK, ea << 2, 64);                                       \
        int pb = __shfl(PK, eb << 2, 64);                                       \
        int pc = __shfl(PK, ec << 2, 64);                                       \
        int pd_ = __shfl(PK, ed_ << 2, 64);                                     \
        uint4 ua = *(const uint4*)(xw + (size_t)(pa >> 3) * 256 + c0);          \
        uint4 ub = *(const uint4*)(xw + (size_t)(pb >> 3) * 256 + c0);          \
        uint4 uc = *(const uint4*)(xw + (size_t)(pc >> 3) * 256 + c0);          \
        uint4 ud = *(const uint4*)(xw + (size_t)(pd_ >> 3) * 256 + c0);         \
        fma8(acc, wa, ua); fma8(acc, wb, ub); fma8(acc, wc, uc);                \
        fma8(acc, wd, ud);                                                      \
    }
#define GATHER1(S, EX, PK)                                                      \
    {                                                                           \
        int e = 2 * (S) + p;                                                    \
        float w = __shfl(EX, (e << 2) | hd, 64);                                \
        int pp = __shfl(PK, e << 2, 64);                                        \
        uint4 u = *(const uint4*)(xw + (size_t)(pp >> 3) * 256 + c0);           \
        fma8(acc, w, u);                                                        \
    }

    for (int base = e0; base < e1; base += 16) {
        int e = base + j4;
        float ex = 0.f;
        int pk = 0;
        if (e < e1) {
            pk = pks[e];
            int t = pk & 7;
            float lg = sb[(size_t)(pk >> 3) * 4 + hq] + c8[t];
            lg = lg > 0.f ? lg : NEG_SLOPE * lg;
            ex = __expf(lg);
            den += ex;
        }
        int cnt = min(16, e1 - base);
        int steps = (cnt + 1) >> 1;
        int s = 0;
        for (; s + 4 <= steps; s += 4) GATHER4(2 * s, ex, pk);
        for (; s < steps; s++) GATHER1(s, ex, pk);
    }
#undef GATHER4
#undef GATHER1

#pragma unroll
    for (int off = 4; off < 64; off <<= 1) den += __shfl_xor(den, off, 64);
    float dv = __shfl(den, hd, 64);
    float deninv = d > 0 ? 1.f / dv : 0.f;

#pragma unroll
    for (int k = 0; k < 8; k++) acc[k] += __shfl_xor(acc[k], 32, 64);

    float4 b0 = load4(bias + c0), b1 = load4(bias + c0 + 4);
    float o[8];
    o[0] = acc[0] * deninv + b0.x; o[1] = acc[1] * deninv + b0.y;
    o[2] = acc[2] * deninv + b0.z; o[3] = acc[3] * deninv + b0.w;
    o[4] = acc[4] * deninv + b1.x; o[5] = acc[5] * deninv + b1.y;
    o[6] = acc[6] * deninv + b1.z; o[7] = acc[7] * deninv + b1.w;

    if constexpr (LNELU) {
        float sum = 0.f, sq = 0.f;
#pragma unroll
        for (int k = 0; k < 8; k++) { sum += o[k]; sq += o[k] * o[k]; }
#pragma unroll
        for (int off = 1; off < 32; off <<= 1) {
            sum += __shfl_xor(sum, off, 64);
            sq  += __shfl_xor(sq, off, 64);
        }
        float mean = sum / 256.f;
        float var = sq / 256.f - mean * mean;
        float rstd = rsqrtf(var + LN_EPS);
        float4 g0v = load4(gamma + c0), g1v = load4(gamma + c0 + 4);
        float4 be0v = load4(beta + c0), be1v = load4(beta + c0 + 4);
        float gm[8] = {g0v.x, g0v.y, g0v.z, g0v.w, g1v.x, g1v.y, g1v.z, g1v.w};
        float bt[8] = {be0v.x, be0v.y, be0v.z, be0v.w, be1v.x, be1v.y, be1v.z, be1v.w};
#pragma unroll
        for (int k = 0; k < 8; k++) {
            float yv = gm[k] * (o[k] - mean) * rstd + bt[k];
            o[k] = yv > 0.f ? yv : expm1f(yv);
        }
    }

    if (p == 0) {
        if constexpr (sizeof(OT) == 2) {
            uint4 pkv;
            pkv.x = f2bu(o[0]) | (f2bu(o[1]) << 16);
            pkv.y = f2bu(o[2]) | (f2bu(o[3]) << 16);
            pkv.z = f2bu(o[4]) | (f2bu(o[5]) << 16);
            pkv.w = f2bu(o[6]) | (f2bu(o[7]) << 16);
            *(uint4*)&out[(size_t)n * 256 + c0] = pkv;
        } else {
            *(float4*)&out[(size_t)n * 256 + c0] = make_float4(o[0], o[1], o[2], o[3]);
            *(float4*)&out[(size_t)n * 256 + c0 + 4] = make_float4(o[4], o[5], o[6], o[7]);
        }
    }
}

// ---------------------------------------------------------------------------
// agg H=1, D=64 (bf16 xw, r-major rows). One wave per node.
// ---------------------------------------------------------------------------
__global__ __launch_bounds__(256) void agg_h1_kernel(
    const int* __restrict__ rowptr, const int* __restrict__ pks,
    const bf16* __restrict__ xw, const float* __restrict__ sb,
    const float* __restrict__ db, const float* __restrict__ ar,
    const float* __restrict__ bias, float* __restrict__ out, int N) {
    int wave = threadIdx.x >> 6;
    int lane = threadIdx.x & 63;
    int n = blockIdx.x * 4 + wave;
    if (n >= N) return;
    int e0 = rowptr[n], e1 = rowptr[n + 1];
    int d = e1 - e0;
    int g = lane & 7, p = lane >> 3;
    int c0 = g * 8;

    float c8[8];
#pragma unroll
    for (int t = 0; t < 8; t++) c8[t] = db[(size_t)n * 8 + t] + ar[t];

    float acc[8] = {0.f, 0.f, 0.f, 0.f, 0.f, 0.f, 0.f, 0.f};
    float den = 0.f;

#define GATH(S, EX, PK)                                                         \
    {                                                                           \
        int e = (S) * 8 + p;                                                    \
        float w = __shfl(EX, e, 64);                                            \
        int pp = __shfl(PK, e, 64);                                             \
        uint4 u = *(const uint4*)(xw + (size_t)(pp >> 3) * 64 + c0);            \
        fma8(acc, w, u);                                                        \
    }

    for (int base = e0; base < e1; base += 64) {
        int e = base + lane;
        float ex = 0.f;
        int pk = 0;
        if (e < e1) {
            pk = pks[e];
            float lg = sb[pk >> 3] + c8[pk & 7];
            lg = lg > 0.f ? lg : NEG_SLOPE * lg;
            ex = __expf(lg);
            den += ex;
        }
        int cnt = min(64, e1 - base);
        int steps = (cnt + 7) >> 3;
        for (int s = 0; s < steps; s++) GATH(s, ex, pk);
    }
#undef GATH

#pragma unroll
    for (int off = 1; off < 64; off <<= 1) den += __shfl_xor(den, off, 64);
    float deninv = d > 0 ? 1.f / den : 0.f;

#pragma unroll
    for (int k = 0; k < 8; k++) {
        acc[k] += __shfl_xor(acc[k], 8, 64);
        acc[k] += __shfl_xor(acc[k], 16, 64);
        acc[k] += __shfl_xor(acc[k], 32, 64);
    }
    if (p == 0) {
        float4 b0 = load4(bias + c0), b1 = load4(bias + c0 + 4);
        *(float4*)&out[(size_t)n * 64 + c0] =
            make_float4(acc[0] * deninv + b0.x, acc[1] * deninv + b0.y,
                        acc[2] * deninv + b0.z, acc[3] * deninv + b0.w);
        *(float4*)&out[(size_t)n * 64 + c0 + 4] =
            make_float4(acc[4] * deninv + b1.x, acc[5] * deninv + b1.y,
                        acc[6] * deninv + b1.z, acc[7] * deninv + b1.w);
    }
}

// ---------------------------------------------------------------------------
extern "C" void kernel_launch(void* const* d_in, const int* in_sizes, int n_in,
                              void* d_out, int out_size, void* d_ws, size_t ws_size,
                              hipStream_t stream) {
    const float* x   = (const float*)d_in[0];
    const int* eidx  = (const int*)d_in[1];
    const int* etyp  = (const int*)d_in[2];
    const float* W0  = (const float*)d_in[3];
    const float* as0 = (const float*)d_in[4];
    const float* ad0 = (const float*)d_in[5];
    const float* ar0 = (const float*)d_in[6];
    const float* bi0 = (const float*)d_in[7];
    const float* W1  = (const float*)d_in[8];
    const float* as1 = (const float*)d_in[9];
    const float* ad1 = (const float*)d_in[10];
    const float* ar1 = (const float*)d_in[11];
    const float* bi1 = (const float*)d_in[12];
    const float* W2  = (const float*)d_in[13];
    const float* as2 = (const float*)d_in[14];
    const float* ad2 = (const float*)d_in[15];
    const float* ar2 = (const float*)d_in[16];
    const float* bi2 = (const float*)d_in[17];
    const float* g0  = (const float*)d_in[18];
    const float* be0 = (const float*)d_in[19];
    const float* g1  = (const float*)d_in[20];
    const float* be1 = (const float*)d_in[21];

    const int E = in_sizes[2];
    const int N = in_sizes[0] / 128;

    size_t off = 0;
    char* wsb = (char*)d_ws;
    auto alloc = [&](size_t bytes) -> void* {
        void* p = wsb + off;
        off += (bytes + 255) & ~(size_t)255;
        return p;
    };
    bf16* xw = (bf16*)alloc((size_t)N * NREL * 256 * sizeof(bf16));  // 204.8 MB
    char* h_region = (char*)alloc((size_t)N * 256 * sizeof(bf16));
    bf16* h  = (bf16*)h_region;
    bf16* xb = (bf16*)h_region;      // x bf16 aliases h (dead before h written)
    float* sb   = (float*)alloc((size_t)N * NREL * 4 * sizeof(float));
    float* db   = (float*)alloc((size_t)N * NREL * 4 * sizeof(float));
    int* cnt    = (int*)alloc((size_t)N * sizeof(int));
    int* rowptr = (int*)alloc((size_t)(N + 1) * sizeof(int));
    int* bsum   = (int*)alloc(64 * sizeof(int));
    int* pks    = (int*)alloc((size_t)E * sizeof(int));
    const int szW0 = NREL * 128 * 256, szW1 = NREL * 256 * 256, szW2 = NREL * 256 * 64;
    bf16* Wh0 = (bf16*)alloc((size_t)szW0 * sizeof(bf16));
    bf16* Wh1 = (bf16*)alloc((size_t)szW1 * sizeof(bf16));
    bf16* Wh2 = (bf16*)alloc((size_t)szW2 * sizeof(bf16));
    bf16* Up0 = (bf16*)alloc((size_t)128 * 64 * sizeof(bf16));
    bf16* Up1 = (bf16*)alloc((size_t)256 * 64 * sizeof(bf16));
    bf16* Up2 = (bf16*)alloc((size_t)256 * 16 * sizeof(bf16));

    const int* srcs = eidx;
    const int* dsts = eidx + E;

    convx_kernel<<<(N * 128 / 4 + 255) / 256, 256, 0, stream>>>(x, xb, N * 128 / 4);
    packw_kernel<<<(szW0 + 255) / 256, 256, 0, stream>>>(W0, Wh0, 128, 256, szW0);
    packw_kernel<<<(szW1 + 255) / 256, 256, 0, stream>>>(W1, Wh1, 256, 256, szW1);
    packw_kernel<<<(szW2 + 255) / 256, 256, 0, stream>>>(W2, Wh2, 256, 64, szW2);
    prepu_kernel<4><<<32, 256, 0, stream>>>(W0, as0, ad0, Up0, 128);
    prepu_kernel<4><<<64, 256, 0, stream>>>(W1, as1, ad1, Up1, 256);
    prepu_kernel<1><<<16, 256, 0, stream>>>(W2, as2, ad2, Up2, 256);

    const int NB = (N + 1023) / 1024;
    hipMemsetAsync(cnt, 0, N * sizeof(int), stream);
    count_kernel<<<(E + 255) / 256, 256, 0, stream>>>(dsts, cnt, E);
    scan1_kernel<<<NB, 1024, 0, stream>>>(cnt, rowptr, bsum, N);
    scan2_kernel<<<1, 64, 0, stream>>>(bsum, NB);
    scan3_kernel<<<NB, 1024, 0, stream>>>(rowptr, bsum, N);
    hipMemsetAsync(cnt, 0, N * sizeof(int), stream);
    fill_kernel<<<(E + 255) / 256, 256, 0, stream>>>(srcs, dsts, etyp, rowptr, cnt, pks, E, N);

    const int MB = (N + 127) / 128;
    const int MBp = ((MB + 7) / 8) * 8;
    const int MB2 = (N + 255) / 256;
    const int MBp2 = ((MB2 + 7) / 8) * 8;
    const int DB = MB;

    // layer 0: in=128 -> D=256, heads=4, LN+ELU
    mfma_gemm_big<<<dim3(MBp2 * 2 * NREL), 512, 0, stream>>>(xb, Wh0, xw, N, 128, 256);
    dots_kernel<128, 4><<<DB, 256, 0, stream>>>(xb, Up0, sb, db, N);
    agg_h4_kernel<true, bf16><<<(N + 3) / 4, 256, 0, stream>>>(
        rowptr, pks, xw, sb, db, ar0, bi0, g0, be0, h, N);

    // layer 1: in=256 -> D=256, heads=4, LN+ELU
    mfma_gemm_big<<<dim3(MBp2 * 2 * NREL), 512, 0, stream>>>(h, Wh1, xw, N, 256, 256);
    dots_kernel<256, 4><<<DB, 256, 0, stream>>>(h, Up1, sb, db, N);
    agg_h4_kernel<true, bf16><<<(N + 3) / 4, 256, 0, stream>>>(
        rowptr, pks, xw, sb, db, ar1, bi1, g1, be1, h, N);

    // layer 2: in=256 -> D=64, heads=1, bf16 xw, fp32 output
    mfma_gemm<64><<<dim3(MBp * 1 * NREL), 256, 0, stream>>>(h, Wh2, xw, N, 256, 64);
    dots_kernel<256, 1><<<DB, 256, 0, stream>>>(h, Up2, sb, db, N);
    agg_h1_kernel<<<(N + 3) / 4, 256, 0, stream>>>(
        rowptr, pks, xw, sb, db, ar2, bi2, (float*)d_out, N);
}

// Round 7
// 590.997 us; speedup vs baseline: 1.0649x; 1.0266x over previous
//
#include <hip/hip_runtime.h>
#include <hip/hip_bf16.h>
#include <math.h>

#define NREL 8
#define LN_EPS 1e-5f
#define NEG_SLOPE 0.2f

typedef __hip_bfloat16 bf16;
typedef __attribute__((ext_vector_type(8))) short short8;
typedef __attribute__((ext_vector_type(4))) float floatx4;

__device__ __forceinline__ unsigned int f2bu(float v) {
    bf16 t = __float2bfloat16(v);
    return (unsigned int)*reinterpret_cast<unsigned short*>(&t);
}

__device__ __forceinline__ float4 load4(const float* p) { return *(const float4*)p; }

__device__ __forceinline__ void fma8(float acc[8], float w, uint4 u) {
    union { unsigned int i; float f; } t;
    t.i = u.x << 16;          acc[0] = fmaf(w, t.f, acc[0]);
    t.i = u.x & 0xffff0000u;  acc[1] = fmaf(w, t.f, acc[1]);
    t.i = u.y << 16;          acc[2] = fmaf(w, t.f, acc[2]);
    t.i = u.y & 0xffff0000u;  acc[3] = fmaf(w, t.f, acc[3]);
    t.i = u.z << 16;          acc[4] = fmaf(w, t.f, acc[4]);
    t.i = u.z & 0xffff0000u;  acc[5] = fmaf(w, t.f, acc[5]);
    t.i = u.w << 16;          acc[6] = fmaf(w, t.f, acc[6]);
    t.i = u.w & 0xffff0000u;  acc[7] = fmaf(w, t.f, acc[7]);
}

__device__ __forceinline__ void async16(const void* g, void* l) {
    __builtin_amdgcn_global_load_lds(
        (const __attribute__((address_space(1))) void*)g,
        (__attribute__((address_space(3))) void*)l, 16, 0, 0);
}

// ---------------------------------------------------------------------------
// CSR build. pk = (rowidx<<3)|rel, rowidx = rel*N + src (r-major xw layout).
// ---------------------------------------------------------------------------
__global__ __launch_bounds__(256) void count_kernel(const int* __restrict__ dst,
                                                    int* __restrict__ cnt, int E) {
    int e = blockIdx.x * 256 + threadIdx.x;
    if (e < E) atomicAdd(&cnt[dst[e]], 1);
}

__global__ __launch_bounds__(1024) void scan1_kernel(const int* __restrict__ cnt,
                                                     int* __restrict__ rowptr,
                                                     int* __restrict__ bsum, int N) {
    __shared__ int sm[1024];
    int tid = threadIdx.x;
    int base = blockIdx.x * 1024;
    int v = (base + tid < N) ? cnt[base + tid] : 0;
    sm[tid] = v;
    __syncthreads();
    for (int off = 1; off < 1024; off <<= 1) {
        int t = (tid >= off) ? sm[tid - off] : 0;
        __syncthreads();
        sm[tid] += t;
        __syncthreads();
    }
    if (base + tid < N) rowptr[base + tid + 1] = sm[tid];
    if (tid == 1023) bsum[blockIdx.x] = sm[1023];
    if (blockIdx.x == 0 && tid == 0) rowptr[0] = 0;
}

__global__ __launch_bounds__(64) void scan2_kernel(int* __restrict__ bsum, int nb) {
    int lane = threadIdx.x;
    int v = (lane < nb) ? bsum[lane] : 0;
    for (int off = 1; off < 64; off <<= 1) {
        int t = __shfl_up(v, off, 64);
        if (lane >= off) v += t;
    }
    int ex = __shfl_up(v, 1, 64);
    if (lane == 0) ex = 0;
    if (lane < nb) bsum[lane] = ex;
}

// scan3 also zeroes cnt (reused as fill's cursor) -- replaces a memset.
__global__ __launch_bounds__(1024) void scan3_kernel(int* __restrict__ rowptr,
                                                     const int* __restrict__ bsum,
                                                     int* __restrict__ cnt, int N) {
    int i = blockIdx.x * 1024 + threadIdx.x;
    if (i < N) {
        rowptr[i + 1] += bsum[blockIdx.x];
        cnt[i] = 0;
    }
}

__global__ __launch_bounds__(256) void fill_kernel(const int* __restrict__ src,
                                                   const int* __restrict__ dst,
                                                   const int* __restrict__ et,
                                                   const int* __restrict__ rowptr,
                                                   int* __restrict__ cursor,
                                                   int* __restrict__ pks, int E, int N) {
    int e = blockIdx.x * 256 + threadIdx.x;
    if (e < E) {
        int d = dst[e];
        int t = et[e];
        int pos = atomicAdd(&cursor[d], 1);
        pks[rowptr[d] + pos] = ((t * N + src[e]) << 3) | t;
    }
}

// ---------------------------------------------------------------------------
// x fp32 -> bf16; also zeroes cnt (replaces the first memset).
// ---------------------------------------------------------------------------
__global__ __launch_bounds__(256) void convx_kernel(const float* __restrict__ x,
                                                    bf16* __restrict__ xb, int total4,
                                                    int* __restrict__ cnt, int N) {
    int i = blockIdx.x * 256 + threadIdx.x;
    if (i < total4) {
        float4 v = ((const float4*)x)[i];
        ushort4 o;
        o.x = (unsigned short)f2bu(v.x);
        o.y = (unsigned short)f2bu(v.y);
        o.z = (unsigned short)f2bu(v.z);
        o.w = (unsigned short)f2bu(v.w);
        ((ushort4*)xb)[i] = o;
    }
    if (i < N) cnt[i] = 0;
}

// ---------------------------------------------------------------------------
// Pack all three W tensors into MFMA-B-fragment order -- single dispatch.
// ---------------------------------------------------------------------------
__device__ __forceinline__ void packw_one(const float* __restrict__ W,
                                          bf16* __restrict__ hi,
                                          int K, int Nc, int i) {
    int kk = i & 7;
    int t1 = i >> 3;
    int nl = t1 & 15;
    int t2 = t1 >> 4;
    int nt = t2 % (Nc / 16);
    int t3 = t2 / (Nc / 16);
    int q = t3 & 3;
    int t4 = t3 >> 2;
    int kt = t4 % (K / 32);
    int r = t4 / (K / 32);
    int k = kt * 32 + q * 8 + kk;
    int n = nt * 16 + nl;
    hi[i] = __float2bfloat16(W[((size_t)r * K + k) * Nc + n]);
}

__global__ __launch_bounds__(256) void packw_all_kernel(
    const float* __restrict__ W0, bf16* __restrict__ Wh0, int sz0,
    const float* __restrict__ W1, bf16* __restrict__ Wh1, int sz1,
    const float* __restrict__ W2, bf16* __restrict__ Wh2, int sz2) {
    int i = blockIdx.x * 256 + threadIdx.x;
    if (i < sz0) packw_one(W0, Wh0, 128, 256, i);
    else if (i < sz0 + sz1) packw_one(W1, Wh1, 256, 256, i - sz0);
    else if (i < sz0 + sz1 + sz2) packw_one(W2, Wh2, 256, 64, i - sz0 - sz1);
}

// ---------------------------------------------------------------------------
// Precompute U in PER-RELATION padded-16-col B-fragment order:
// Up[((r*(K/32)+kt)*4+q)*16*8 + nl*8 + kk], nl<2*HH valid (sd=nl/HH, h=nl%HH),
// value = sum_c W[r][k][h*64+c] * a_{sd}[h][c]; nl>=2*HH zero-padded.
// Consumed directly by the fused-dots GEMM epilogues. Single dispatch.
// ---------------------------------------------------------------------------
__device__ __forceinline__ void prepu_one(const float* __restrict__ W,
                                          const float* __restrict__ as_,
                                          const float* __restrict__ ad_,
                                          bf16* __restrict__ Up,
                                          int K, int HH, int idx) {
    int kk = idx & 7;
    int t = idx >> 3;
    int nl = t & 15; t >>= 4;
    int q = t & 3; t >>= 2;
    int nkt = K >> 5;
    int kt = t % nkt;
    int r = t / nkt;
    int k = kt * 32 + q * 8 + kk;
    float s = 0.f;
    if (nl < 2 * HH) {
        int sd = nl / HH, h = nl % HH;
        const float* a = (sd ? ad_ : as_) + h * 64;
        const float* w = W + ((size_t)r * K + k) * (HH * 64) + h * 64;
#pragma unroll
        for (int c = 0; c < 16; c++) {
            float4 wv4 = load4(w + c * 4);
            float4 av4 = load4(a + c * 4);
            s += wv4.x * av4.x + wv4.y * av4.y + wv4.z * av4.z + wv4.w * av4.w;
        }
    }
    Up[idx] = __float2bfloat16(s);
}

__global__ __launch_bounds__(256) void prepu_all_kernel(
    const float* __restrict__ W0, const float* __restrict__ as0,
    const float* __restrict__ ad0, bf16* __restrict__ Up0,
    const float* __restrict__ W1, const float* __restrict__ as1,
    const float* __restrict__ ad1, bf16* __restrict__ Up1,
    const float* __restrict__ W2, const float* __restrict__ as2,
    const float* __restrict__ ad2, bf16* __restrict__ Up2) {
    const int sz0 = NREL * 128 * 16;   // 16384
    const int sz1 = NREL * 256 * 16;   // 32768
    const int sz2 = NREL * 256 * 16;   // 32768
    int i = blockIdx.x * 256 + threadIdx.x;
    if (i < sz0) prepu_one(W0, as0, ad0, Up0, 128, 4, i);
    else if (i < sz0 + sz1) prepu_one(W1, as1, ad1, Up1, 256, 4, i - sz0);
    else if (i < sz0 + sz1 + sz2) prepu_one(W2, as2, ad2, Up2, 256, 1, i - sz0 - sz1);
}

// ---------------------------------------------------------------------------
// Big MFMA GEMM: 256x128 tile, 8 waves (4m x 2n), RING-3, one barrier/K-step,
// r-major C. FUSED DOTS: y==0, wn==0 waves additionally compute A.U_r via one
// extra MFMA per K-step (U_r staged once in LDS, 16 padded cols: sd*4+h) and
// scatter sb/db in the epilogue -- removes the standalone dots dispatches.
// ---------------------------------------------------------------------------
__global__ __launch_bounds__(512) void mfma_gemm_big(const bf16* __restrict__ A,
                                                     const bf16* __restrict__ Bh,
                                                     const bf16* __restrict__ Up,
                                                     bf16* __restrict__ C,
                                                     float* __restrict__ sb,
                                                     float* __restrict__ db,
                                                     int M, int K, int Nc) {
    const int gy = Nc / 128;          // 2
    const int nyr = gy * NREL;        // 16
    int id = blockIdx.x;
    int res = id & 7;
    int q = id >> 3;
    int j_ = q % nyr;
    int mg = q / nyr;
    int mt = mg * 8 + res;
    const int MBcnt = (M + 255) >> 8;
    if (mt >= MBcnt) return;
    const int m0 = mt * 256;
    const int y = j_ % gy;
    const int r = j_ / gy;
    const int n0 = y * 128;

    const int tid = threadIdx.x;
    const int wv = tid >> 6;
    const int lane = tid & 63;
    const int wm = wv & 3, wn = wv >> 2;
    const int ml = lane & 15, mq = lane >> 4;
    const bool doU = (y == 0) && (wn == 0);

    __shared__ __align__(16) short lsA[3][8192];    // 3 x 16KB A tiles
    __shared__ __align__(16) short lsBh[3][4096];   // 3 x 8KB B tiles
    __shared__ __align__(16) short lsU[4096];       // U_r, up to 8KB

    floatx4 acc[4][4];
#pragma unroll
    for (int i = 0; i < 4; i++)
#pragma unroll
        for (int j = 0; j < 4; j++) acc[i][j] = (floatx4)(0.f);
    floatx4 uacc[4];
#pragma unroll
    for (int i = 0; i < 4; i++) uacc[i] = (floatx4)(0.f);

    const int nkt = K >> 5;

    // A staging: 1024 slots (16KB), 2 per thread.
    const bf16* aptr[2];
    short* adst[2];
#pragma unroll
    for (int c = 0; c < 2; c++) {
        int idx = c * 512 + tid;
        int rgrp = idx >> 8;
        int it = (idx >> 6) & 3;
        int qq = (idx >> 4) & 3;
        int ml_ = idx & 15;
        int row = m0 + rgrp * 64 + it * 16 + ml_;
        row = row < M ? row : M - 1;
        aptr[c] = A + (size_t)row * K + qq * 8;
        adst[c] = &lsA[0][(c * 512 + wv * 64) * 8];
    }
    // B staging: 512 slots (8KB), 1 per thread.
    const bf16* bptr;
    short* bdst;
    {
        int qq = tid >> 7;
        int rem = tid & 127;
        int nt = rem >> 4;
        int nl = rem & 15;
        bptr = Bh + (size_t)r * K * Nc +
               ((size_t)(qq * (Nc / 16) + (n0 >> 4) + nt) * 16 + nl) * 8;
        bdst = &lsBh[0][(wv * 64) * 8];
    }
    const size_t bstep = (size_t)32 * Nc;

    // U staging: K*16 bf16 = K*2 x 16B loads (256 @K=128, 512 @K=256).
    if (y == 0 && tid < K * 2)
        async16(Up + (size_t)r * K * 16 + (size_t)tid * 8, lsU + (wv * 64) * 8);

#define STAGE_BIG(BUF)                                                         \
    {                                                                          \
        _Pragma("unroll")                                                      \
        for (int c = 0; c < 2; c++) {                                          \
            async16(aptr[c], adst[c] + (BUF) * 8192);                          \
            aptr[c] += 32;                                                     \
        }                                                                      \
        async16(bptr, bdst + (BUF) * 4096);                                    \
        bptr += bstep;                                                         \
    }

    STAGE_BIG(0);
    STAGE_BIG(1);

    int cur = 0;
    for (int kt = 0; kt < nkt; kt++) {
        if (kt + 1 < nkt) {
            asm volatile("s_waitcnt vmcnt(3)" ::: "memory");
        } else {
            asm volatile("s_waitcnt vmcnt(0)" ::: "memory");
        }
        __builtin_amdgcn_s_barrier();

        if (kt + 2 < nkt) {
            int stg = (cur == 0) ? 2 : cur - 1;   // (cur+2)%3
            STAGE_BIG(stg);
        }

        short8 af[4];
#pragma unroll
        for (int i = 0; i < 4; i++)
            af[i] = *(const short8*)&lsA[cur][(wm * 256 + i * 64 + lane) * 8];

#pragma unroll
        for (int j = 0; j < 4; j++) {
            int ntl = wn * 4 + j;
            short8 bh = *(const short8*)&lsBh[cur][(mq * 128 + ntl * 16 + ml) * 8];
#pragma unroll
            for (int i = 0; i < 4; i++)
                acc[i][j] = __builtin_amdgcn_mfma_f32_16x16x32_bf16(af[i], bh, acc[i][j], 0, 0, 0);
        }
        if (doU) {
            short8 bu = *(const short8*)&lsU[((kt * 4 + mq) * 16 + ml) * 8];
#pragma unroll
            for (int i = 0; i < 4; i++)
                uacc[i] = __builtin_amdgcn_mfma_f32_16x16x32_bf16(af[i], bu, uacc[i], 0, 0, 0);
        }
        cur = (cur == 2) ? 0 : cur + 1;
    }
#undef STAGE_BIG

    // ---- fused dots epilogue: scatter sb (r-major) / db (node-major) ----
    if (doU && ml < 8) {
        int sd = ml >> 2, h = ml & 3;
#pragma unroll
        for (int i = 0; i < 4; i++)
#pragma unroll
            for (int reg = 0; reg < 4; reg++) {
                int m = m0 + wm * 64 + i * 16 + mq * 4 + reg;
                if (m < M) {
                    float v = uacc[i][reg];
                    if (sd == 0) sb[((size_t)r * M + m) * 4 + h] = v;
                    else db[((size_t)m * 8 + r) * 4 + h] = v;
                }
            }
    }

    // ---- C store via XOR-swizzled LDS repack, r-major cached stores ----
    {
        bf16* rep = (bf16*)lsA;                  // 64 x 128 bf16 = 16KB
#pragma unroll
        for (int i = 0; i < 4; i++) {
            __syncthreads();
#pragma unroll
            for (int j = 0; j < 4; j++) {
                int col = wn * 64 + j * 16 + ml;
#pragma unroll
                for (int reg = 0; reg < 4; reg++) {
                    int rrow = wm * 16 + mq * 4 + reg;
                    int blk = (col >> 3) ^ (((rrow >> 2) & 3) << 1);
                    rep[rrow * 128 + blk * 8 + (col & 7)] =
                        __float2bfloat16(acc[i][j][reg]);
                }
            }
            __syncthreads();
#pragma unroll
            for (int rr = 0; rr < 2; rr++) {
                int lrow = rr * 32 + (tid >> 4);
                int cblk = (tid & 15) ^ (((lrow >> 2) & 3) << 1);
                uint4 v = *(const uint4*)&rep[lrow * 128 + cblk * 8];
                int m = m0 + (lrow >> 4) * 64 + i * 16 + (lrow & 15);
                if (m < M)
                    *(uint4*)&C[((size_t)r * M + m) * Nc + n0 + (tid & 15) * 8] = v;
            }
        }
    }
}

// ---------------------------------------------------------------------------
// MFMA GEMM (128-tile, 4 waves) — layer-2 (BN=64). RING-3, one barrier,
// r-major C, fused dots (HH=1: U cols sd in {0,1}, h=0).
// ---------------------------------------------------------------------------
template <int BN>
__global__ __launch_bounds__(256) void mfma_gemm(const bf16* __restrict__ A,
                                                 const bf16* __restrict__ Bh,
                                                 const bf16* __restrict__ Up,
                                                 bf16* __restrict__ C,
                                                 float* __restrict__ sb,
                                                 float* __restrict__ db,
                                                 int M, int K, int Nc) {
    const int gy = Nc / BN;
    const int nyr = gy * NREL;
    int id = blockIdx.x;
    int res = id & 7;
    int q = id >> 3;
    int j_ = q % nyr;
    int mg = q / nyr;
    int mt = mg * 8 + res;
    const int MBcnt = (M + 127) >> 7;
    if (mt >= MBcnt) return;
    const int m0 = mt * 128;
    const int y = j_ % gy;
    const int r = j_ / gy;
    const int n0 = y * BN;

    const int tid = threadIdx.x;
    const int wv = tid >> 6;
    const int lane = tid & 63;
    const int ml = lane & 15, mq = lane >> 4;
    const bool doU = (y == 0) && (wv < 2);

    __shared__ __align__(16) short lsA[3][4096];
    __shared__ __align__(16) short lsBh[3][BN * 32];
    __shared__ __align__(16) short lsU[4096];

    const int wn0 = (wv >> 1) * (BN / 2);
    constexpr int JT = BN / 32;
    constexpr int NBL = BN / 64;
    constexpr int NL = 2 + NBL;

    floatx4 acc[4][JT];
#pragma unroll
    for (int i = 0; i < 4; i++)
#pragma unroll
        for (int j = 0; j < JT; j++) acc[i][j] = (floatx4)(0.f);
    floatx4 uacc[4];
#pragma unroll
    for (int i = 0; i < 4; i++) uacc[i] = (floatx4)(0.f);

    const bf16* bh_r = Bh + (size_t)r * K * Nc;
    const int nkt = K >> 5;

    const bf16* aptr[2];
    short* adst[2];
#pragma unroll
    for (int c = 0; c < 2; c++) {
        int idx = c * 256 + tid;
        int half = idx >> 8;
        int it = (idx >> 6) & 3;
        int qq = (idx >> 4) & 3;
        int ml_ = idx & 15;
        int row = m0 + half * 64 + it * 16 + ml_;
        row = row < M ? row : M - 1;
        aptr[c] = A + (size_t)row * K + qq * 8;
        adst[c] = &lsA[0][(c * 256 + wv * 64) * 8];
    }
    const bf16* bhptr[NBL];
    short* bhdst[NBL];
#pragma unroll
    for (int c = 0; c < NBL; c++) {
        int idx = c * 256 + tid;
        int qq = idx / BN;
        int rem = idx % BN;
        int nt = rem >> 4;
        int nl = rem & 15;
        size_t goff = ((size_t)(qq * (Nc / 16) + (n0 >> 4) + nt) * 16 + nl) * 8;
        bhptr[c] = bh_r + goff;
        bhdst[c] = &lsBh[0][(c * 256 + wv * 64) * 8];
    }
    const size_t bstep = (size_t)32 * Nc;

    // U staging: K*16 bf16 -> K*2 loads of 16B; 256 threads -> 2 per thread @K=256.
    if (y == 0) {
#pragma unroll
        for (int c = 0; c < 2; c++) {
            int idx = c * 256 + tid;
            if (idx < K * 2)
                async16(Up + (size_t)r * K * 16 + (size_t)idx * 8,
                        lsU + (c * 256 + wv * 64) * 8);
        }
    }

#define STAGE_SM(BUF)                                                          \
    {                                                                          \
        _Pragma("unroll")                                                      \
        for (int c = 0; c < 2; c++) {                                          \
            async16(aptr[c], adst[c] + (BUF) * 4096);                          \
            aptr[c] += 32;                                                     \
        }                                                                      \
        _Pragma("unroll")                                                      \
        for (int c = 0; c < NBL; c++) {                                        \
            async16(bhptr[c], bhdst[c] + (BUF) * (BN * 32));                   \
            bhptr[c] += bstep;                                                 \
        }                                                                      \
    }

    STAGE_SM(0);
    STAGE_SM(1);

    int cur = 0;
    for (int kt = 0; kt < nkt; kt++) {
        if (kt + 1 < nkt) {
            asm volatile("s_waitcnt vmcnt(%0)" :: "n"(NL) : "memory");
        } else {
            asm volatile("s_waitcnt vmcnt(0)" ::: "memory");
        }
        __builtin_amdgcn_s_barrier();

        if (kt + 2 < nkt) {
            int stg = (cur == 0) ? 2 : cur - 1;
            STAGE_SM(stg);
        }

        short8 af[4];
#pragma unroll
        for (int i = 0; i < 4; i++)
            af[i] = *(const short8*)&lsA[cur][(((wv & 1) * 4 + i) * 64 + lane) * 8];

#pragma unroll
        for (int j = 0; j < JT; j++) {
            int ntl = (wv >> 1) * JT + j;
            int boff = ((lane >> 4) * BN + ntl * 16 + (lane & 15)) * 8;
            short8 bh = *(const short8*)&lsBh[cur][boff];
#pragma unroll
            for (int i = 0; i < 4; i++)
                acc[i][j] = __builtin_amdgcn_mfma_f32_16x16x32_bf16(af[i], bh, acc[i][j], 0, 0, 0);
        }
        if (doU) {
            short8 bu = *(const short8*)&lsU[((kt * 4 + mq) * 16 + ml) * 8];
#pragma unroll
            for (int i = 0; i < 4; i++)
                uacc[i] = __builtin_amdgcn_mfma_f32_16x16x32_bf16(af[i], bu, uacc[i], 0, 0, 0);
        }
        cur = (cur == 2) ? 0 : cur + 1;
    }
#undef STAGE_SM

    // ---- fused dots epilogue (HH=1): cols 0->sb, 1->db ----
    if (doU && ml < 2) {
#pragma unroll
        for (int i = 0; i < 4; i++)
#pragma unroll
            for (int reg = 0; reg < 4; reg++) {
                int m = m0 + (wv & 1) * 64 + i * 16 + mq * 4 + reg;
                if (m < M) {
                    float v = uacc[i][reg];
                    if (ml == 0) sb[(size_t)r * M + m] = v;
                    else db[(size_t)m * 8 + r] = v;
                }
            }
    }

    {
        bf16* rep = (bf16*)lsA;                  // 32 rows x BN cols
        constexpr int CPT = 8;
        constexpr int TPR = BN / CPT;
        constexpr int RPR = 256 / TPR;
        constexpr int NRND = 32 / RPR;
#pragma unroll
        for (int i = 0; i < 4; i++) {
            __syncthreads();
#pragma unroll
            for (int j = 0; j < JT; j++) {
                int col = wn0 + j * 16 + ml;
#pragma unroll
                for (int reg = 0; reg < 4; reg++) {
                    int rrow = (wv & 1) * 16 + mq * 4 + reg;
                    int blk = (col / CPT) ^ (((rrow >> 2) & 3) << 1);
                    rep[rrow * BN + blk * CPT + (col % CPT)] =
                        __float2bfloat16(acc[i][j][reg]);
                }
            }
            __syncthreads();
#pragma unroll
            for (int rr = 0; rr < NRND; rr++) {
                int lrow = rr * RPR + tid / TPR;
                int cblk = (tid % TPR) ^ (((lrow >> 2) & 3) << 1);
                uint4 v = *(const uint4*)&rep[lrow * BN + cblk * CPT];
                int m = m0 + (lrow >> 4) * 64 + i * 16 + (lrow & 15);
                if (m < M)
                    *(uint4*)&C[((size_t)r * M + m) * Nc + n0 + (tid % TPR) * CPT] = v;
            }
        }
    }
}

// ---------------------------------------------------------------------------
// agg H=4, D=256 (bf16 xw, r-major rows via pk>>3). One wave per node.
// ---------------------------------------------------------------------------
template <bool LNELU, typename OT>
__global__ __launch_bounds__(256) void agg_h4_kernel(
    const int* __restrict__ rowptr, const int* __restrict__ pks,
    const bf16* __restrict__ xw, const float* __restrict__ sb,
    const float* __restrict__ db, const float* __restrict__ ar,
    const float* __restrict__ bias, const float* __restrict__ gamma,
    const float* __restrict__ beta, OT* __restrict__ out, int N) {
    int wave = threadIdx.x >> 6;
    int lane = threadIdx.x & 63;
    int n = blockIdx.x * 4 + wave;
    if (n >= N) return;
    int e0 = rowptr[n], e1 = rowptr[n + 1];
    int d = e1 - e0;
    int j4 = lane >> 2, hq = lane & 3;
    int g = lane & 31, p = lane >> 5;
    int c0 = g * 8, hd = g >> 3;

    float c8[8];
#pragma unroll
    for (int t = 0; t < 8; t++)
        c8[t] = db[((size_t)n * 8 + t) * 4 + hq] + ar[t * 4 + hq];

    float acc[8] = {0.f, 0.f, 0.f, 0.f, 0.f, 0.f, 0.f, 0.f};
    float den = 0.f;

#define GATHER4(EBASE, EX, PK)                                                  \
    {                                                                           \
        int ea = (EBASE) + p, eb = ea + 2, ec = ea + 4, ed_ = ea + 6;           \
        float wa = __shfl(EX, (ea << 2) | hd, 64);                              \
        float wb = __shfl(EX, (eb << 2) | hd, 64);                              \
        float wc = __shfl(EX, (ec << 2) | hd, 64);                              \
        float wd = __shfl(EX, (ed_ << 2) | hd, 64);                             \
        int pa = __shfl(PK, ea << 2, 64);                                       \
        int pb = __shfl(PK, eb << 2, 64);                                       \
        int pc = __shfl(PK, ec << 2, 64);                                       \
        int pd_ = __shfl(PK, ed_ << 2, 64);                                     \
        uint4 ua = *(const uint4*)(xw + (size_t)(pa >> 3) * 256 + c0);          \
        uint4 ub = *(const uint4*)(xw + (size_t)(pb >> 3) * 256 + c0);          \
        uint4 uc = *(const uint4*)(xw + (size_t)(pc >> 3) * 256 + c0);          \
        uint4 ud = *(const uint4*)(xw + (size_t)(pd_ >> 3) * 256 + c0);         \
        fma8(acc, wa, ua); fma8(acc, wb, ub); fma8(acc, wc, uc);                \
        fma8(acc, wd, ud);                                                      \
    }
#define GATHER1(S, EX, PK)                                                      \
    {                                                                           \
        int e = 2 * (S) + p;                                                    \
        float w = __shfl(EX, (e << 2) | hd, 64);                                \
        int pp = __shfl(PK, e << 2, 64);                                        \
        uint4 u = *(const uint4*)(xw + (size_t)(pp >> 3) * 256 + c0);           \
        fma8(acc, w, u);                                                        \
    }

    for (int base = e0; base < e1; base += 16) {
        int e = base + j4;
        float ex = 0.f;
        int pk = 0;
        if (e < e1) {
            pk = pks[e];
            int t = pk & 7;
            float lg = sb[(size_t)(pk >> 3) * 4 + hq] + c8[t];
            lg = lg > 0.f ? lg : NEG_SLOPE * lg;
            ex = __expf(lg);
            den += ex;
        }
        int cnt = min(16, e1 - base);
        int steps = (cnt + 1) >> 1;
        int s = 0;
        for (; s + 4 <= steps; s += 4) GATHER4(2 * s, ex, pk);
        for (; s < steps; s++) GATHER1(s, ex, pk);
    }
#undef GATHER4
#undef GATHER1

#pragma unroll
    for (int off = 4; off < 64; off <<= 1) den += __shfl_xor(den, off, 64);
    float dv = __shfl(den, hd, 64);
    float deninv = d > 0 ? 1.f / dv : 0.f;

#pragma unroll
    for (int k = 0; k < 8; k++) acc[k] += __shfl_xor(acc[k], 32, 64);

    float4 b0 = load4(bias + c0), b1 = load4(bias + c0 + 4);
    float o[8];
    o[0] = acc[0] * deninv + b0.x; o[1] = acc[1] * deninv + b0.y;
    o[2] = acc[2] * deninv + b0.z; o[3] = acc[3] * deninv + b0.w;
    o[4] = acc[4] * deninv + b1.x; o[5] = acc[5] * deninv + b1.y;
    o[6] = acc[6] * deninv + b1.z; o[7] = acc[7] * deninv + b1.w;

    if constexpr (LNELU) {
        float sum = 0.f, sq = 0.f;
#pragma unroll
        for (int k = 0; k < 8; k++) { sum += o[k]; sq += o[k] * o[k]; }
#pragma unroll
        for (int off = 1; off < 32; off <<= 1) {
            sum += __shfl_xor(sum, off, 64);
            sq  += __shfl_xor(sq, off, 64);
        }
        float mean = sum / 256.f;
        float var = sq / 256.f - mean * mean;
        float rstd = rsqrtf(var + LN_EPS);
        float4 g0v = load4(gamma + c0), g1v = load4(gamma + c0 + 4);
        float4 be0v = load4(beta + c0), be1v = load4(beta + c0 + 4);
        float gm[8] = {g0v.x, g0v.y, g0v.z, g0v.w, g1v.x, g1v.y, g1v.z, g1v.w};
        float bt[8] = {be0v.x, be0v.y, be0v.z, be0v.w, be1v.x, be1v.y, be1v.z, be1v.w};
#pragma unroll
        for (int k = 0; k < 8; k++) {
            float yv = gm[k] * (o[k] - mean) * rstd + bt[k];
            o[k] = yv > 0.f ? yv : expm1f(yv);
        }
    }

    if (p == 0) {
        if constexpr (sizeof(OT) == 2) {
            uint4 pkv;
            pkv.x = f2bu(o[0]) | (f2bu(o[1]) << 16);
            pkv.y = f2bu(o[2]) | (f2bu(o[3]) << 16);
            pkv.z = f2bu(o[4]) | (f2bu(o[5]) << 16);
            pkv.w = f2bu(o[6]) | (f2bu(o[7]) << 16);
            *(uint4*)&out[(size_t)n * 256 + c0] = pkv;
        } else {
            *(float4*)&out[(size_t)n * 256 + c0] = make_float4(o[0], o[1], o[2], o[3]);
            *(float4*)&out[(size_t)n * 256 + c0 + 4] = make_float4(o[4], o[5], o[6], o[7]);
        }
    }
}

// ---------------------------------------------------------------------------
// agg H=1, D=64 (bf16 xw, r-major rows). One wave per node.
// ---------------------------------------------------------------------------
__global__ __launch_bounds__(256) void agg_h1_kernel(
    const int* __restrict__ rowptr, const int* __restrict__ pks,
    const bf16* __restrict__ xw, const float* __restrict__ sb,
    const float* __restrict__ db, const float* __restrict__ ar,
    const float* __restrict__ bias, float* __restrict__ out, int N) {
    int wave = threadIdx.x >> 6;
    int lane = threadIdx.x & 63;
    int n = blockIdx.x * 4 + wave;
    if (n >= N) return;
    int e0 = rowptr[n], e1 = rowptr[n + 1];
    int d = e1 - e0;
    int g = lane & 7, p = lane >> 3;
    int c0 = g * 8;

    float c8[8];
#pragma unroll
    for (int t = 0; t < 8; t++) c8[t] = db[(size_t)n * 8 + t] + ar[t];

    float acc[8] = {0.f, 0.f, 0.f, 0.f, 0.f, 0.f, 0.f, 0.f};
    float den = 0.f;

#define GATH(S, EX, PK)                                                         \
    {                                                                           \
        int e = (S) * 8 + p;                                                    \
        float w = __shfl(EX, e, 64);                                            \
        int pp = __shfl(PK, e, 64);                                             \
        uint4 u = *(const uint4*)(xw + (size_t)(pp >> 3) * 64 + c0);            \
        fma8(acc, w, u);                                                        \
    }

    for (int base = e0; base < e1; base += 64) {
        int e = base + lane;
        float ex = 0.f;
        int pk = 0;
        if (e < e1) {
            pk = pks[e];
            float lg = sb[pk >> 3] + c8[pk & 7];
            lg = lg > 0.f ? lg : NEG_SLOPE * lg;
            ex = __expf(lg);
            den += ex;
        }
        int cnt = min(64, e1 - base);
        int steps = (cnt + 7) >> 3;
        for (int s = 0; s < steps; s++) GATH(s, ex, pk);
    }
#undef GATH

#pragma unroll
    for (int off = 1; off < 64; off <<= 1) den += __shfl_xor(den, off, 64);
    float deninv = d > 0 ? 1.f / den : 0.f;

#pragma unroll
    for (int k = 0; k < 8; k++) {
        acc[k] += __shfl_xor(acc[k], 8, 64);
        acc[k] += __shfl_xor(acc[k], 16, 64);
        acc[k] += __shfl_xor(acc[k], 32, 64);
    }
    if (p == 0) {
        float4 b0 = load4(bias + c0), b1 = load4(bias + c0 + 4);
        *(float4*)&out[(size_t)n * 64 + c0] =
            make_float4(acc[0] * deninv + b0.x, acc[1] * deninv + b0.y,
                        acc[2] * deninv + b0.z, acc[3] * deninv + b0.w);
        *(float4*)&out[(size_t)n * 64 + c0 + 4] =
            make_float4(acc[4] * deninv + b1.x, acc[5] * deninv + b1.y,
                        acc[6] * deninv + b1.z, acc[7] * deninv + b1.w);
    }
}

// ---------------------------------------------------------------------------
extern "C" void kernel_launch(void* const* d_in, const int* in_sizes, int n_in,
                              void* d_out, int out_size, void* d_ws, size_t ws_size,
                              hipStream_t stream) {
    const float* x   = (const float*)d_in[0];
    const int* eidx  = (const int*)d_in[1];
    const int* etyp  = (const int*)d_in[2];
    const float* W0  = (const float*)d_in[3];
    const float* as0 = (const float*)d_in[4];
    const float* ad0 = (const float*)d_in[5];
    const float* ar0 = (const float*)d_in[6];
    const float* bi0 = (const float*)d_in[7];
    const float* W1  = (const float*)d_in[8];
    const float* as1 = (const float*)d_in[9];
    const float* ad1 = (const float*)d_in[10];
    const float* ar1 = (const float*)d_in[11];
    const float* bi1 = (const float*)d_in[12];
    const float* W2  = (const float*)d_in[13];
    const float* as2 = (const float*)d_in[14];
    const float* ad2 = (const float*)d_in[15];
    const float* ar2 = (const float*)d_in[16];
    const float* bi2 = (const float*)d_in[17];
    const float* g0  = (const float*)d_in[18];
    const float* be0 = (const float*)d_in[19];
    const float* g1  = (const float*)d_in[20];
    const float* be1 = (const float*)d_in[21];

    const int E = in_sizes[2];
    const int N = in_sizes[0] / 128;

    size_t off = 0;
    char* wsb = (char*)d_ws;
    auto alloc = [&](size_t bytes) -> void* {
        void* p = wsb + off;
        off += (bytes + 255) & ~(size_t)255;
        return p;
    };
    bf16* xw = (bf16*)alloc((size_t)N * NREL * 256 * sizeof(bf16));  // 204.8 MB
    char* h_region = (char*)alloc((size_t)N * 256 * sizeof(bf16));
    bf16* h  = (bf16*)h_region;
    bf16* xb = (bf16*)h_region;      // x bf16 aliases h (dead before h written)
    float* sb   = (float*)alloc((size_t)N * NREL * 4 * sizeof(float));
    float* db   = (float*)alloc((size_t)N * NREL * 4 * sizeof(float));
    int* cnt    = (int*)alloc((size_t)N * sizeof(int));
    int* rowptr = (int*)alloc((size_t)(N + 1) * sizeof(int));
    int* bsum   = (int*)alloc(64 * sizeof(int));
    int* pks    = (int*)alloc((size_t)E * sizeof(int));
    const int szW0 = NREL * 128 * 256, szW1 = NREL * 256 * 256, szW2 = NREL * 256 * 64;
    bf16* Wh0 = (bf16*)alloc((size_t)szW0 * sizeof(bf16));
    bf16* Wh1 = (bf16*)alloc((size_t)szW1 * sizeof(bf16));
    bf16* Wh2 = (bf16*)alloc((size_t)szW2 * sizeof(bf16));
    bf16* Up0 = (bf16*)alloc((size_t)NREL * 128 * 16 * sizeof(bf16));
    bf16* Up1 = (bf16*)alloc((size_t)NREL * 256 * 16 * sizeof(bf16));
    bf16* Up2 = (bf16*)alloc((size_t)NREL * 256 * 16 * sizeof(bf16));

    const int* srcs = eidx;
    const int* dsts = eidx + E;

    convx_kernel<<<(N * 128 / 4 + 255) / 256, 256, 0, stream>>>(
        x, xb, N * 128 / 4, cnt, N);
    const int szWtot = szW0 + szW1 + szW2;
    packw_all_kernel<<<(szWtot + 255) / 256, 256, 0, stream>>>(
        W0, Wh0, szW0, W1, Wh1, szW1, W2, Wh2, szW2);
    const int szUtot = NREL * 128 * 16 + NREL * 256 * 16 + NREL * 256 * 16;
    prepu_all_kernel<<<(szUtot + 255) / 256, 256, 0, stream>>>(
        W0, as0, ad0, Up0, W1, as1, ad1, Up1, W2, as2, ad2, Up2);

    const int NB = (N + 1023) / 1024;
    count_kernel<<<(E + 255) / 256, 256, 0, stream>>>(dsts, cnt, E);
    scan1_kernel<<<NB, 1024, 0, stream>>>(cnt, rowptr, bsum, N);
    scan2_kernel<<<1, 64, 0, stream>>>(bsum, NB);
    scan3_kernel<<<NB, 1024, 0, stream>>>(rowptr, bsum, cnt, N);
    fill_kernel<<<(E + 255) / 256, 256, 0, stream>>>(srcs, dsts, etyp, rowptr, cnt, pks, E, N);

    const int MB = (N + 127) / 128;
    const int MBp = ((MB + 7) / 8) * 8;
    const int MB2 = (N + 255) / 256;
    const int MBp2 = ((MB2 + 7) / 8) * 8;

    // layer 0: in=128 -> D=256, heads=4, LN+ELU
    mfma_gemm_big<<<dim3(MBp2 * 2 * NREL), 512, 0, stream>>>(
        xb, Wh0, Up0, xw, sb, db, N, 128, 256);
    agg_h4_kernel<true, bf16><<<(N + 3) / 4, 256, 0, stream>>>(
        rowptr, pks, xw, sb, db, ar0, bi0, g0, be0, h, N);

    // layer 1: in=256 -> D=256, heads=4, LN+ELU
    mfma_gemm_big<<<dim3(MBp2 * 2 * NREL), 512, 0, stream>>>(
        h, Wh1, Up1, xw, sb, db, N, 256, 256);
    agg_h4_kernel<true, bf16><<<(N + 3) / 4, 256, 0, stream>>>(
        rowptr, pks, xw, sb, db, ar1, bi1, g1, be1, h, N);

    // layer 2: in=256 -> D=64, heads=1, fp32 output
    mfma_gemm<64><<<dim3(MBp * 1 * NREL), 256, 0, stream>>>(
        h, Wh2, Up2, xw, sb, db, N, 256, 64);
    agg_h1_kernel<<<(N + 3) / 4, 256, 0, stream>>>(
        rowptr, pks, xw, sb, db, ar2, bi2, (float*)d_out, N);
}

// Round 8
// 586.729 us; speedup vs baseline: 1.0726x; 1.0073x over previous
//
#include <hip/hip_runtime.h>
#include <hip/hip_bf16.h>
#include <math.h>

#define NREL 8
#define LN_EPS 1e-5f
#define NEG_SLOPE 0.2f

typedef __hip_bfloat16 bf16;
typedef __attribute__((ext_vector_type(8))) short short8;
typedef __attribute__((ext_vector_type(4))) float floatx4;

__device__ __forceinline__ unsigned int f2bu(float v) {
    bf16 t = __float2bfloat16(v);
    return (unsigned int)*reinterpret_cast<unsigned short*>(&t);
}

__device__ __forceinline__ float4 load4(const float* p) { return *(const float4*)p; }

__device__ __forceinline__ void fma8(float acc[8], float w, uint4 u) {
    union { unsigned int i; float f; } t;
    t.i = u.x << 16;          acc[0] = fmaf(w, t.f, acc[0]);
    t.i = u.x & 0xffff0000u;  acc[1] = fmaf(w, t.f, acc[1]);
    t.i = u.y << 16;          acc[2] = fmaf(w, t.f, acc[2]);
    t.i = u.y & 0xffff0000u;  acc[3] = fmaf(w, t.f, acc[3]);
    t.i = u.z << 16;          acc[4] = fmaf(w, t.f, acc[4]);
    t.i = u.z & 0xffff0000u;  acc[5] = fmaf(w, t.f, acc[5]);
    t.i = u.w << 16;          acc[6] = fmaf(w, t.f, acc[6]);
    t.i = u.w & 0xffff0000u;  acc[7] = fmaf(w, t.f, acc[7]);
}

__device__ __forceinline__ void async16(const void* g, void* l) {
    __builtin_amdgcn_global_load_lds(
        (const __attribute__((address_space(1))) void*)g,
        (__attribute__((address_space(3))) void*)l, 16, 0, 0);
}

// ---------------------------------------------------------------------------
// CSR build. pk = (rowidx<<3)|rel, rowidx = rel*N + src (r-major xw layout).
// (count is fused into prep_all_kernel; cnt zeroed by convx.)
// ---------------------------------------------------------------------------
__global__ __launch_bounds__(1024) void scan1_kernel(const int* __restrict__ cnt,
                                                     int* __restrict__ rowptr,
                                                     int* __restrict__ bsum, int N) {
    __shared__ int sm[1024];
    int tid = threadIdx.x;
    int base = blockIdx.x * 1024;
    int v = (base + tid < N) ? cnt[base + tid] : 0;
    sm[tid] = v;
    __syncthreads();
    for (int off = 1; off < 1024; off <<= 1) {
        int t = (tid >= off) ? sm[tid - off] : 0;
        __syncthreads();
        sm[tid] += t;
        __syncthreads();
    }
    if (base + tid < N) rowptr[base + tid + 1] = sm[tid];
    if (tid == 1023) bsum[blockIdx.x] = sm[1023];
    if (blockIdx.x == 0 && tid == 0) rowptr[0] = 0;
}

__global__ __launch_bounds__(64) void scan2_kernel(int* __restrict__ bsum, int nb) {
    int lane = threadIdx.x;
    int v = (lane < nb) ? bsum[lane] : 0;
    for (int off = 1; off < 64; off <<= 1) {
        int t = __shfl_up(v, off, 64);
        if (lane >= off) v += t;
    }
    int ex = __shfl_up(v, 1, 64);
    if (lane == 0) ex = 0;
    if (lane < nb) bsum[lane] = ex;
}

// scan3 also zeroes cnt (reused as fill's cursor) -- replaces a memset.
__global__ __launch_bounds__(1024) void scan3_kernel(int* __restrict__ rowptr,
                                                     const int* __restrict__ bsum,
                                                     int* __restrict__ cnt, int N) {
    int i = blockIdx.x * 1024 + threadIdx.x;
    if (i < N) {
        rowptr[i + 1] += bsum[blockIdx.x];
        cnt[i] = 0;
    }
}

__global__ __launch_bounds__(256) void fill_kernel(const int* __restrict__ src,
                                                   const int* __restrict__ dst,
                                                   const int* __restrict__ et,
                                                   const int* __restrict__ rowptr,
                                                   int* __restrict__ cursor,
                                                   int* __restrict__ pks, int E, int N) {
    int e = blockIdx.x * 256 + threadIdx.x;
    if (e < E) {
        int d = dst[e];
        int t = et[e];
        int pos = atomicAdd(&cursor[d], 1);
        pks[rowptr[d] + pos] = ((t * N + src[e]) << 3) | t;
    }
}

// ---------------------------------------------------------------------------
// x fp32 -> bf16; also zeroes cnt (count runs in the NEXT dispatch).
// ---------------------------------------------------------------------------
__global__ __launch_bounds__(256) void convx_kernel(const float* __restrict__ x,
                                                    bf16* __restrict__ xb, int total4,
                                                    int* __restrict__ cnt, int N) {
    int i = blockIdx.x * 256 + threadIdx.x;
    if (i < total4) {
        float4 v = ((const float4*)x)[i];
        ushort4 o;
        o.x = (unsigned short)f2bu(v.x);
        o.y = (unsigned short)f2bu(v.y);
        o.z = (unsigned short)f2bu(v.z);
        o.w = (unsigned short)f2bu(v.w);
        ((ushort4*)xb)[i] = o;
    }
    if (i < N) cnt[i] = 0;
}

// ---------------------------------------------------------------------------
// Pack W into MFMA-B-fragment order (one element per thread-slot).
// ---------------------------------------------------------------------------
__device__ __forceinline__ void packw_one(const float* __restrict__ W,
                                          bf16* __restrict__ hi,
                                          int K, int Nc, int i) {
    int kk = i & 7;
    int t1 = i >> 3;
    int nl = t1 & 15;
    int t2 = t1 >> 4;
    int nt = t2 % (Nc / 16);
    int t3 = t2 / (Nc / 16);
    int q = t3 & 3;
    int t4 = t3 >> 2;
    int kt = t4 % (K / 32);
    int r = t4 / (K / 32);
    int k = kt * 32 + q * 8 + kk;
    int n = nt * 16 + nl;
    hi[i] = __float2bfloat16(W[((size_t)r * K + k) * Nc + n]);
}

// ---------------------------------------------------------------------------
// Precompute U in PER-RELATION padded-16-col B-fragment order:
// Up[((r*(K/32)+kt)*4+q)*16*8 + nl*8 + kk], nl<2*HH valid (sd=nl/HH, h=nl%HH),
// value = sum_c W[r][k][h*64+c] * a_{sd}[h][c]; nl>=2*HH zero-padded.
// ---------------------------------------------------------------------------
__device__ __forceinline__ void prepu_one(const float* __restrict__ W,
                                          const float* __restrict__ as_,
                                          const float* __restrict__ ad_,
                                          bf16* __restrict__ Up,
                                          int K, int HH, int idx) {
    int kk = idx & 7;
    int t = idx >> 3;
    int nl = t & 15; t >>= 4;
    int q = t & 3; t >>= 2;
    int nkt = K >> 5;
    int kt = t % nkt;
    int r = t / nkt;
    int k = kt * 32 + q * 8 + kk;
    float s = 0.f;
    if (nl < 2 * HH) {
        int sd = nl / HH, h = nl % HH;
        const float* a = (sd ? ad_ : as_) + h * 64;
        const float* w = W + ((size_t)r * K + k) * (HH * 64) + h * 64;
#pragma unroll
        for (int c = 0; c < 16; c++) {
            float4 wv4 = load4(w + c * 4);
            float4 av4 = load4(a + c * 4);
            s += wv4.x * av4.x + wv4.y * av4.y + wv4.z * av4.z + wv4.w * av4.w;
        }
    }
    Up[idx] = __float2bfloat16(s);
}

// ---------------------------------------------------------------------------
// Single preamble dispatch: packs all 3 W tensors, computes all 3 U panels,
// and does the CSR edge count (cnt zeroed by convx, which precedes on the
// same stream). Grid = szW total (917504 threads >= E and >= szU total).
// ---------------------------------------------------------------------------
__global__ __launch_bounds__(256) void prep_all_kernel(
    const float* __restrict__ W0, bf16* __restrict__ Wh0, int sz0,
    const float* __restrict__ W1, bf16* __restrict__ Wh1, int sz1,
    const float* __restrict__ W2, bf16* __restrict__ Wh2, int sz2,
    const float* __restrict__ as0, const float* __restrict__ ad0, bf16* __restrict__ Up0,
    const float* __restrict__ as1, const float* __restrict__ ad1, bf16* __restrict__ Up1,
    const float* __restrict__ as2, const float* __restrict__ ad2, bf16* __restrict__ Up2,
    const int* __restrict__ dsts, int* __restrict__ cnt, int E) {
    int i = blockIdx.x * 256 + threadIdx.x;
    if (i < sz0) packw_one(W0, Wh0, 128, 256, i);
    else if (i < sz0 + sz1) packw_one(W1, Wh1, 256, 256, i - sz0);
    else if (i < sz0 + sz1 + sz2) packw_one(W2, Wh2, 256, 64, i - sz0 - sz1);
    const int u0 = NREL * 128 * 16, u1 = NREL * 256 * 16, u2 = NREL * 256 * 16;
    if (i < u0) prepu_one(W0, as0, ad0, Up0, 128, 4, i);
    else if (i < u0 + u1) prepu_one(W1, as1, ad1, Up1, 256, 4, i - u0);
    else if (i < u0 + u1 + u2) prepu_one(W2, as2, ad2, Up2, 256, 1, i - u0 - u1);
    if (i < E) atomicAdd(&cnt[dsts[i]], 1);
}

// ---------------------------------------------------------------------------
// Big MFMA GEMM: 256x128 tile, 8 waves (4m x 2n), RING-3, one barrier/K-step,
// r-major C. FUSED DOTS: y==0, wn==0 waves additionally compute A.U_r via one
// extra MFMA per K-step (U_r staged once in LDS) and scatter sb/db.
// ---------------------------------------------------------------------------
__global__ __launch_bounds__(512) void mfma_gemm_big(const bf16* __restrict__ A,
                                                     const bf16* __restrict__ Bh,
                                                     const bf16* __restrict__ Up,
                                                     bf16* __restrict__ C,
                                                     float* __restrict__ sb,
                                                     float* __restrict__ db,
                                                     int M, int K, int Nc) {
    const int gy = Nc / 128;          // 2
    const int nyr = gy * NREL;        // 16
    int id = blockIdx.x;
    int res = id & 7;
    int q = id >> 3;
    int j_ = q % nyr;
    int mg = q / nyr;
    int mt = mg * 8 + res;
    const int MBcnt = (M + 255) >> 8;
    if (mt >= MBcnt) return;
    const int m0 = mt * 256;
    const int y = j_ % gy;
    const int r = j_ / gy;
    const int n0 = y * 128;

    const int tid = threadIdx.x;
    const int wv = tid >> 6;
    const int lane = tid & 63;
    const int wm = wv & 3, wn = wv >> 2;
    const int ml = lane & 15, mq = lane >> 4;
    const bool doU = (y == 0) && (wn == 0);

    __shared__ __align__(16) short lsA[3][8192];    // 3 x 16KB A tiles
    __shared__ __align__(16) short lsBh[3][4096];   // 3 x 8KB B tiles
    __shared__ __align__(16) short lsU[4096];       // U_r, up to 8KB

    floatx4 acc[4][4];
#pragma unroll
    for (int i = 0; i < 4; i++)
#pragma unroll
        for (int j = 0; j < 4; j++) acc[i][j] = (floatx4)(0.f);
    floatx4 uacc[4];
#pragma unroll
    for (int i = 0; i < 4; i++) uacc[i] = (floatx4)(0.f);

    const int nkt = K >> 5;

    // A staging: 1024 slots (16KB), 2 per thread.
    const bf16* aptr[2];
    short* adst[2];
#pragma unroll
    for (int c = 0; c < 2; c++) {
        int idx = c * 512 + tid;
        int rgrp = idx >> 8;
        int it = (idx >> 6) & 3;
        int qq = (idx >> 4) & 3;
        int ml_ = idx & 15;
        int row = m0 + rgrp * 64 + it * 16 + ml_;
        row = row < M ? row : M - 1;
        aptr[c] = A + (size_t)row * K + qq * 8;
        adst[c] = &lsA[0][(c * 512 + wv * 64) * 8];
    }
    // B staging: 512 slots (8KB), 1 per thread.
    const bf16* bptr;
    short* bdst;
    {
        int qq = tid >> 7;
        int rem = tid & 127;
        int nt = rem >> 4;
        int nl = rem & 15;
        bptr = Bh + (size_t)r * K * Nc +
               ((size_t)(qq * (Nc / 16) + (n0 >> 4) + nt) * 16 + nl) * 8;
        bdst = &lsBh[0][(wv * 64) * 8];
    }
    const size_t bstep = (size_t)32 * Nc;

    // U staging: K*16 bf16 = K*2 x 16B loads (256 @K=128, 512 @K=256).
    if (y == 0 && tid < K * 2)
        async16(Up + (size_t)r * K * 16 + (size_t)tid * 8, lsU + (wv * 64) * 8);

#define STAGE_BIG(BUF)                                                         \
    {                                                                          \
        _Pragma("unroll")                                                      \
        for (int c = 0; c < 2; c++) {                                          \
            async16(aptr[c], adst[c] + (BUF) * 8192);                          \
            aptr[c] += 32;                                                     \
        }                                                                      \
        async16(bptr, bdst + (BUF) * 4096);                                    \
        bptr += bstep;                                                         \
    }

    STAGE_BIG(0);
    STAGE_BIG(1);

    int cur = 0;
    for (int kt = 0; kt < nkt; kt++) {
        if (kt + 1 < nkt) {
            asm volatile("s_waitcnt vmcnt(3)" ::: "memory");
        } else {
            asm volatile("s_waitcnt vmcnt(0)" ::: "memory");
        }
        __builtin_amdgcn_s_barrier();

        if (kt + 2 < nkt) {
            int stg = (cur == 0) ? 2 : cur - 1;   // (cur+2)%3
            STAGE_BIG(stg);
        }

        short8 af[4];
#pragma unroll
        for (int i = 0; i < 4; i++)
            af[i] = *(const short8*)&lsA[cur][(wm * 256 + i * 64 + lane) * 8];

#pragma unroll
        for (int j = 0; j < 4; j++) {
            int ntl = wn * 4 + j;
            short8 bh = *(const short8*)&lsBh[cur][(mq * 128 + ntl * 16 + ml) * 8];
#pragma unroll
            for (int i = 0; i < 4; i++)
                acc[i][j] = __builtin_amdgcn_mfma_f32_16x16x32_bf16(af[i], bh, acc[i][j], 0, 0, 0);
        }
        if (doU) {
            short8 bu = *(const short8*)&lsU[((kt * 4 + mq) * 16 + ml) * 8];
#pragma unroll
            for (int i = 0; i < 4; i++)
                uacc[i] = __builtin_amdgcn_mfma_f32_16x16x32_bf16(af[i], bu, uacc[i], 0, 0, 0);
        }
        cur = (cur == 2) ? 0 : cur + 1;
    }
#undef STAGE_BIG

    // ---- fused dots epilogue: scatter sb (r-major) / db (node-major) ----
    if (doU && ml < 8) {
        int sd = ml >> 2, h = ml & 3;
#pragma unroll
        for (int i = 0; i < 4; i++)
#pragma unroll
            for (int reg = 0; reg < 4; reg++) {
                int m = m0 + wm * 64 + i * 16 + mq * 4 + reg;
                if (m < M) {
                    float v = uacc[i][reg];
                    if (sd == 0) sb[((size_t)r * M + m) * 4 + h] = v;
                    else db[((size_t)m * 8 + r) * 4 + h] = v;
                }
            }
    }

    // ---- C store via XOR-swizzled LDS repack, r-major cached stores ----
    {
        bf16* rep = (bf16*)lsA;                  // 64 x 128 bf16 = 16KB
#pragma unroll
        for (int i = 0; i < 4; i++) {
            __syncthreads();
#pragma unroll
            for (int j = 0; j < 4; j++) {
                int col = wn * 64 + j * 16 + ml;
#pragma unroll
                for (int reg = 0; reg < 4; reg++) {
                    int rrow = wm * 16 + mq * 4 + reg;
                    int blk = (col >> 3) ^ (((rrow >> 2) & 3) << 1);
                    rep[rrow * 128 + blk * 8 + (col & 7)] =
                        __float2bfloat16(acc[i][j][reg]);
                }
            }
            __syncthreads();
#pragma unroll
            for (int rr = 0; rr < 2; rr++) {
                int lrow = rr * 32 + (tid >> 4);
                int cblk = (tid & 15) ^ (((lrow >> 2) & 3) << 1);
                uint4 v = *(const uint4*)&rep[lrow * 128 + cblk * 8];
                int m = m0 + (lrow >> 4) * 64 + i * 16 + (lrow & 15);
                if (m < M)
                    *(uint4*)&C[((size_t)r * M + m) * Nc + n0 + (tid & 15) * 8] = v;
            }
        }
    }
}

// ---------------------------------------------------------------------------
// MFMA GEMM (128-tile, 4 waves) — layer-2 (BN=64). RING-3, one barrier,
// r-major C, fused dots (HH=1: U cols sd in {0,1}, h=0).
// ---------------------------------------------------------------------------
template <int BN>
__global__ __launch_bounds__(256) void mfma_gemm(const bf16* __restrict__ A,
                                                 const bf16* __restrict__ Bh,
                                                 const bf16* __restrict__ Up,
                                                 bf16* __restrict__ C,
                                                 float* __restrict__ sb,
                                                 float* __restrict__ db,
                                                 int M, int K, int Nc) {
    const int gy = Nc / BN;
    const int nyr = gy * NREL;
    int id = blockIdx.x;
    int res = id & 7;
    int q = id >> 3;
    int j_ = q % nyr;
    int mg = q / nyr;
    int mt = mg * 8 + res;
    const int MBcnt = (M + 127) >> 7;
    if (mt >= MBcnt) return;
    const int m0 = mt * 128;
    const int y = j_ % gy;
    const int r = j_ / gy;
    const int n0 = y * BN;

    const int tid = threadIdx.x;
    const int wv = tid >> 6;
    const int lane = tid & 63;
    const int ml = lane & 15, mq = lane >> 4;
    const bool doU = (y == 0) && (wv < 2);

    __shared__ __align__(16) short lsA[3][4096];
    __shared__ __align__(16) short lsBh[3][BN * 32];
    __shared__ __align__(16) short lsU[4096];

    const int wn0 = (wv >> 1) * (BN / 2);
    constexpr int JT = BN / 32;
    constexpr int NBL = BN / 64;
    constexpr int NL = 2 + NBL;

    floatx4 acc[4][JT];
#pragma unroll
    for (int i = 0; i < 4; i++)
#pragma unroll
        for (int j = 0; j < JT; j++) acc[i][j] = (floatx4)(0.f);
    floatx4 uacc[4];
#pragma unroll
    for (int i = 0; i < 4; i++) uacc[i] = (floatx4)(0.f);

    const bf16* bh_r = Bh + (size_t)r * K * Nc;
    const int nkt = K >> 5;

    const bf16* aptr[2];
    short* adst[2];
#pragma unroll
    for (int c = 0; c < 2; c++) {
        int idx = c * 256 + tid;
        int half = idx >> 8;
        int it = (idx >> 6) & 3;
        int qq = (idx >> 4) & 3;
        int ml_ = idx & 15;
        int row = m0 + half * 64 + it * 16 + ml_;
        row = row < M ? row : M - 1;
        aptr[c] = A + (size_t)row * K + qq * 8;
        adst[c] = &lsA[0][(c * 256 + wv * 64) * 8];
    }
    const bf16* bhptr[NBL];
    short* bhdst[NBL];
#pragma unroll
    for (int c = 0; c < NBL; c++) {
        int idx = c * 256 + tid;
        int qq = idx / BN;
        int rem = idx % BN;
        int nt = rem >> 4;
        int nl = rem & 15;
        size_t goff = ((size_t)(qq * (Nc / 16) + (n0 >> 4) + nt) * 16 + nl) * 8;
        bhptr[c] = bh_r + goff;
        bhdst[c] = &lsBh[0][(c * 256 + wv * 64) * 8];
    }
    const size_t bstep = (size_t)32 * Nc;

    // U staging: K*16 bf16 -> K*2 loads of 16B; 2 per thread @K=256.
    if (y == 0) {
#pragma unroll
        for (int c = 0; c < 2; c++) {
            int idx = c * 256 + tid;
            if (idx < K * 2)
                async16(Up + (size_t)r * K * 16 + (size_t)idx * 8,
                        lsU + (c * 256 + wv * 64) * 8);
        }
    }

#define STAGE_SM(BUF)                                                          \
    {                                                                          \
        _Pragma("unroll")                                                      \
        for (int c = 0; c < 2; c++) {                                          \
            async16(aptr[c], adst[c] + (BUF) * 4096);                          \
            aptr[c] += 32;                                                     \
        }                                                                      \
        _Pragma("unroll")                                                      \
        for (int c = 0; c < NBL; c++) {                                        \
            async16(bhptr[c], bhdst[c] + (BUF) * (BN * 32));                   \
            bhptr[c] += bstep;                                                 \
        }                                                                      \
    }

    STAGE_SM(0);
    STAGE_SM(1);

    int cur = 0;
    for (int kt = 0; kt < nkt; kt++) {
        if (kt + 1 < nkt) {
            asm volatile("s_waitcnt vmcnt(%0)" :: "n"(NL) : "memory");
        } else {
            asm volatile("s_waitcnt vmcnt(0)" ::: "memory");
        }
        __builtin_amdgcn_s_barrier();

        if (kt + 2 < nkt) {
            int stg = (cur == 0) ? 2 : cur - 1;
            STAGE_SM(stg);
        }

        short8 af[4];
#pragma unroll
        for (int i = 0; i < 4; i++)
            af[i] = *(const short8*)&lsA[cur][(((wv & 1) * 4 + i) * 64 + lane) * 8];

#pragma unroll
        for (int j = 0; j < JT; j++) {
            int ntl = (wv >> 1) * JT + j;
            int boff = ((lane >> 4) * BN + ntl * 16 + (lane & 15)) * 8;
            short8 bh = *(const short8*)&lsBh[cur][boff];
#pragma unroll
            for (int i = 0; i < 4; i++)
                acc[i][j] = __builtin_amdgcn_mfma_f32_16x16x32_bf16(af[i], bh, acc[i][j], 0, 0, 0);
        }
        if (doU) {
            short8 bu = *(const short8*)&lsU[((kt * 4 + mq) * 16 + ml) * 8];
#pragma unroll
            for (int i = 0; i < 4; i++)
                uacc[i] = __builtin_amdgcn_mfma_f32_16x16x32_bf16(af[i], bu, uacc[i], 0, 0, 0);
        }
        cur = (cur == 2) ? 0 : cur + 1;
    }
#undef STAGE_SM

    // ---- fused dots epilogue (HH=1): cols 0->sb, 1->db ----
    if (doU && ml < 2) {
#pragma unroll
        for (int i = 0; i < 4; i++)
#pragma unroll
            for (int reg = 0; reg < 4; reg++) {
                int m = m0 + (wv & 1) * 64 + i * 16 + mq * 4 + reg;
                if (m < M) {
                    float v = uacc[i][reg];
                    if (ml == 0) sb[(size_t)r * M + m] = v;
                    else db[(size_t)m * 8 + r] = v;
                }
            }
    }

    {
        bf16* rep = (bf16*)lsA;                  // 32 rows x BN cols
        constexpr int CPT = 8;
        constexpr int TPR = BN / CPT;
        constexpr int RPR = 256 / TPR;
        constexpr int NRND = 32 / RPR;
#pragma unroll
        for (int i = 0; i < 4; i++) {
            __syncthreads();
#pragma unroll
            for (int j = 0; j < JT; j++) {
                int col = wn0 + j * 16 + ml;
#pragma unroll
                for (int reg = 0; reg < 4; reg++) {
                    int rrow = (wv & 1) * 16 + mq * 4 + reg;
                    int blk = (col / CPT) ^ (((rrow >> 2) & 3) << 1);
                    rep[rrow * BN + blk * CPT + (col % CPT)] =
                        __float2bfloat16(acc[i][j][reg]);
                }
            }
            __syncthreads();
#pragma unroll
            for (int rr = 0; rr < NRND; rr++) {
                int lrow = rr * RPR + tid / TPR;
                int cblk = (tid % TPR) ^ (((lrow >> 2) & 3) << 1);
                uint4 v = *(const uint4*)&rep[lrow * BN + cblk * CPT];
                int m = m0 + (lrow >> 4) * 64 + i * 16 + (lrow & 15);
                if (m < M)
                    *(uint4*)&C[((size_t)r * M + m) * Nc + n0 + (tid % TPR) * CPT] = v;
            }
        }
    }
}

// ---------------------------------------------------------------------------
// agg H=4, D=256 (bf16 xw, r-major rows via pk>>3). One wave per node.
// ---------------------------------------------------------------------------
template <bool LNELU, typename OT>
__global__ __launch_bounds__(256) void agg_h4_kernel(
    const int* __restrict__ rowptr, const int* __restrict__ pks,
    const bf16* __restrict__ xw, const float* __restrict__ sb,
    const float* __restrict__ db, const float* __restrict__ ar,
    const float* __restrict__ bias, const float* __restrict__ gamma,
    const float* __restrict__ beta, OT* __restrict__ out, int N) {
    int wave = threadIdx.x >> 6;
    int lane = threadIdx.x & 63;
    int n = blockIdx.x * 4 + wave;
    if (n >= N) return;
    int e0 = rowptr[n], e1 = rowptr[n + 1];
    int d = e1 - e0;
    int j4 = lane >> 2, hq = lane & 3;
    int g = lane & 31, p = lane >> 5;
    int c0 = g * 8, hd = g >> 3;

    float c8[8];
#pragma unroll
    for (int t = 0; t < 8; t++)
        c8[t] = db[((size_t)n * 8 + t) * 4 + hq] + ar[t * 4 + hq];

    float acc[8] = {0.f, 0.f, 0.f, 0.f, 0.f, 0.f, 0.f, 0.f};
    float den = 0.f;

#define GATHER4(EBASE, EX, PK)                                                  \
    {                                                                           \
        int ea = (EBASE) + p, eb = ea + 2, ec = ea + 4, ed_ = ea + 6;           \
        float wa = __shfl(EX, (ea << 2) | hd, 64);                              \
        float wb = __shfl(EX, (eb << 2) | hd, 64);                              \
        float wc = __shfl(EX, (ec << 2) | hd, 64);                              \
        float wd = __shfl(EX, (ed_ << 2) | hd, 64);                             \
        int pa = __shfl(PK, ea << 2, 64);                                       \
        int pb = __shfl(PK, eb << 2, 64);                                       \
        int pc = __shfl(PK, ec << 2, 64);                                       \
        int pd_ = __shfl(PK, ed_ << 2, 64);                                     \
        uint4 ua = *(const uint4*)(xw + (size_t)(pa >> 3) * 256 + c0);          \
        uint4 ub = *(const uint4*)(xw + (size_t)(pb >> 3) * 256 + c0);          \
        uint4 uc = *(const uint4*)(xw + (size_t)(pc >> 3) * 256 + c0);          \
        uint4 ud = *(const uint4*)(xw + (size_t)(pd_ >> 3) * 256 + c0);         \
        fma8(acc, wa, ua); fma8(acc, wb, ub); fma8(acc, wc, uc);                \
        fma8(acc, wd, ud);                                                      \
    }
#define GATHER1(S, EX, PK)                                                      \
    {                                                                           \
        int e = 2 * (S) + p;                                                    \
        float w = __shfl(EX, (e << 2) | hd, 64);                                \
        int pp = __shfl(PK, e << 2, 64);                                        \
        uint4 u = *(const uint4*)(xw + (size_t)(pp >> 3) * 256 + c0);           \
        fma8(acc, w, u);                                                        \
    }

    for (int base = e0; base < e1; base += 16) {
        int e = base + j4;
        float ex = 0.f;
        int pk = 0;
        if (e < e1) {
            pk = pks[e];
            int t = pk & 7;
            float lg = sb[(size_t)(pk >> 3) * 4 + hq] + c8[t];
            lg = lg > 0.f ? lg : NEG_SLOPE * lg;
            ex = __expf(lg);
            den += ex;
        }
        int cnt = min(16, e1 - base);
        int steps = (cnt + 1) >> 1;
        int s = 0;
        for (; s + 4 <= steps; s += 4) GATHER4(2 * s, ex, pk);
        for (; s < steps; s++) GATHER1(s, ex, pk);
    }
#undef GATHER4
#undef GATHER1

#pragma unroll
    for (int off = 4; off < 64; off <<= 1) den += __shfl_xor(den, off, 64);
    float dv = __shfl(den, hd, 64);
    float deninv = d > 0 ? 1.f / dv : 0.f;

#pragma unroll
    for (int k = 0; k < 8; k++) acc[k] += __shfl_xor(acc[k], 32, 64);

    float4 b0 = load4(bias + c0), b1 = load4(bias + c0 + 4);
    float o[8];
    o[0] = acc[0] * deninv + b0.x; o[1] = acc[1] * deninv + b0.y;
    o[2] = acc[2] * deninv + b0.z; o[3] = acc[3] * deninv + b0.w;
    o[4] = acc[4] * deninv + b1.x; o[5] = acc[5] * deninv + b1.y;
    o[6] = acc[6] * deninv + b1.z; o[7] = acc[7] * deninv + b1.w;

    if constexpr (LNELU) {
        float sum = 0.f, sq = 0.f;
#pragma unroll
        for (int k = 0; k < 8; k++) { sum += o[k]; sq += o[k] * o[k]; }
#pragma unroll
        for (int off = 1; off < 32; off <<= 1) {
            sum += __shfl_xor(sum, off, 64);
            sq  += __shfl_xor(sq, off, 64);
        }
        float mean = sum / 256.f;
        float var = sq / 256.f - mean * mean;
        float rstd = rsqrtf(var + LN_EPS);
        float4 g0v = load4(gamma + c0), g1v = load4(gamma + c0 + 4);
        float4 be0v = load4(beta + c0), be1v = load4(beta + c0 + 4);
        float gm[8] = {g0v.x, g0v.y, g0v.z, g0v.w, g1v.x, g1v.y, g1v.z, g1v.w};
        float bt[8] = {be0v.x, be0v.y, be0v.z, be0v.w, be1v.x, be1v.y, be1v.z, be1v.w};
#pragma unroll
        for (int k = 0; k < 8; k++) {
            float yv = gm[k] * (o[k] - mean) * rstd + bt[k];
            o[k] = yv > 0.f ? yv : expm1f(yv);
        }
    }

    if (p == 0) {
        if constexpr (sizeof(OT) == 2) {
            uint4 pkv;
            pkv.x = f2bu(o[0]) | (f2bu(o[1]) << 16);
            pkv.y = f2bu(o[2]) | (f2bu(o[3]) << 16);
            pkv.z = f2bu(o[4]) | (f2bu(o[5]) << 16);
            pkv.w = f2bu(o[6]) | (f2bu(o[7]) << 16);
            *(uint4*)&out[(size_t)n * 256 + c0] = pkv;
        } else {
            *(float4*)&out[(size_t)n * 256 + c0] = make_float4(o[0], o[1], o[2], o[3]);
            *(float4*)&out[(size_t)n * 256 + c0 + 4] = make_float4(o[4], o[5], o[6], o[7]);
        }
    }
}

// ---------------------------------------------------------------------------
// agg H=1, D=64 (bf16 xw, r-major rows). One wave per node.
// ---------------------------------------------------------------------------
__global__ __launch_bounds__(256) void agg_h1_kernel(
    const int* __restrict__ rowptr, const int* __restrict__ pks,
    const bf16* __restrict__ xw, const float* __restrict__ sb,
    const float* __restrict__ db, const float* __restrict__ ar,
    const float* __restrict__ bias, float* __restrict__ out, int N) {
    int wave = threadIdx.x >> 6;
    int lane = threadIdx.x & 63;
    int n = blockIdx.x * 4 + wave;
    if (n >= N) return;
    int e0 = rowptr[n], e1 = rowptr[n + 1];
    int d = e1 - e0;
    int g = lane & 7, p = lane >> 3;
    int c0 = g * 8;

    float c8[8];
#pragma unroll
    for (int t = 0; t < 8; t++) c8[t] = db[(size_t)n * 8 + t] + ar[t];

    float acc[8] = {0.f, 0.f, 0.f, 0.f, 0.f, 0.f, 0.f, 0.f};
    float den = 0.f;

#define GATH(S, EX, PK)                                                         \
    {                                                                           \
        int e = (S) * 8 + p;                                                    \
        float w = __shfl(EX, e, 64);                                            \
        int pp = __shfl(PK, e, 64);                                             \
        uint4 u = *(const uint4*)(xw + (size_t)(pp >> 3) * 64 + c0);            \
        fma8(acc, w, u);                                                        \
    }

    for (int base = e0; base < e1; base += 64) {
        int e = base + lane;
        float ex = 0.f;
        int pk = 0;
        if (e < e1) {
            pk = pks[e];
            float lg = sb[pk >> 3] + c8[pk & 7];
            lg = lg > 0.f ? lg : NEG_SLOPE * lg;
            ex = __expf(lg);
            den += ex;
        }
        int cnt = min(64, e1 - base);
        int steps = (cnt + 7) >> 3;
        for (int s = 0; s < steps; s++) GATH(s, ex, pk);
    }
#undef GATH

#pragma unroll
    for (int off = 1; off < 64; off <<= 1) den += __shfl_xor(den, off, 64);
    float deninv = d > 0 ? 1.f / den : 0.f;

#pragma unroll
    for (int k = 0; k < 8; k++) {
        acc[k] += __shfl_xor(acc[k], 8, 64);
        acc[k] += __shfl_xor(acc[k], 16, 64);
        acc[k] += __shfl_xor(acc[k], 32, 64);
    }
    if (p == 0) {
        float4 b0 = load4(bias + c0), b1 = load4(bias + c0 + 4);
        *(float4*)&out[(size_t)n * 64 + c0] =
            make_float4(acc[0] * deninv + b0.x, acc[1] * deninv + b0.y,
                        acc[2] * deninv + b0.z, acc[3] * deninv + b0.w);
        *(float4*)&out[(size_t)n * 64 + c0 + 4] =
            make_float4(acc[4] * deninv + b1.x, acc[5] * deninv + b1.y,
                        acc[6] * deninv + b1.z, acc[7] * deninv + b1.w);
    }
}

// ---------------------------------------------------------------------------
extern "C" void kernel_launch(void* const* d_in, const int* in_sizes, int n_in,
                              void* d_out, int out_size, void* d_ws, size_t ws_size,
                              hipStream_t stream) {
    const float* x   = (const float*)d_in[0];
    const int* eidx  = (const int*)d_in[1];
    const int* etyp  = (const int*)d_in[2];
    const float* W0  = (const float*)d_in[3];
    const float* as0 = (const float*)d_in[4];
    const float* ad0 = (const float*)d_in[5];
    const float* ar0 = (const float*)d_in[6];
    const float* bi0 = (const float*)d_in[7];
    const float* W1  = (const float*)d_in[8];
    const float* as1 = (const float*)d_in[9];
    const float* ad1 = (const float*)d_in[10];
    const float* ar1 = (const float*)d_in[11];
    const float* bi1 = (const float*)d_in[12];
    const float* W2  = (const float*)d_in[13];
    const float* as2 = (const float*)d_in[14];
    const float* ad2 = (const float*)d_in[15];
    const float* ar2 = (const float*)d_in[16];
    const float* bi2 = (const float*)d_in[17];
    const float* g0  = (const float*)d_in[18];
    const float* be0 = (const float*)d_in[19];
    const float* g1  = (const float*)d_in[20];
    const float* be1 = (const float*)d_in[21];

    const int E = in_sizes[2];
    const int N = in_sizes[0] / 128;

    size_t off = 0;
    char* wsb = (char*)d_ws;
    auto alloc = [&](size_t bytes) -> void* {
        void* p = wsb + off;
        off += (bytes + 255) & ~(size_t)255;
        return p;
    };
    bf16* xw = (bf16*)alloc((size_t)N * NREL * 256 * sizeof(bf16));  // 204.8 MB
    char* h_region = (char*)alloc((size_t)N * 256 * sizeof(bf16));
    bf16* h  = (bf16*)h_region;
    bf16* xb = (bf16*)h_region;      // x bf16 aliases h (dead before h written)
    float* sb   = (float*)alloc((size_t)N * NREL * 4 * sizeof(float));
    float* db   = (float*)alloc((size_t)N * NREL * 4 * sizeof(float));
    int* cnt    = (int*)alloc((size_t)N * sizeof(int));
    int* rowptr = (int*)alloc((size_t)(N + 1) * sizeof(int));
    int* bsum   = (int*)alloc(64 * sizeof(int));
    int* pks    = (int*)alloc((size_t)E * sizeof(int));
    const int szW0 = NREL * 128 * 256, szW1 = NREL * 256 * 256, szW2 = NREL * 256 * 64;
    bf16* Wh0 = (bf16*)alloc((size_t)szW0 * sizeof(bf16));
    bf16* Wh1 = (bf16*)alloc((size_t)szW1 * sizeof(bf16));
    bf16* Wh2 = (bf16*)alloc((size_t)szW2 * sizeof(bf16));
    bf16* Up0 = (bf16*)alloc((size_t)NREL * 128 * 16 * sizeof(bf16));
    bf16* Up1 = (bf16*)alloc((size_t)NREL * 256 * 16 * sizeof(bf16));
    bf16* Up2 = (bf16*)alloc((size_t)NREL * 256 * 16 * sizeof(bf16));

    const int* srcs = eidx;
    const int* dsts = eidx + E;

    // convx zeroes cnt; prep_all (next dispatch, same stream) does the count.
    convx_kernel<<<(N * 128 / 4 + 255) / 256, 256, 0, stream>>>(
        x, xb, N * 128 / 4, cnt, N);
    const int szWtot = szW0 + szW1 + szW2;   // 917504 >= E and >= szU total
    prep_all_kernel<<<(szWtot + 255) / 256, 256, 0, stream>>>(
        W0, Wh0, szW0, W1, Wh1, szW1, W2, Wh2, szW2,
        as0, ad0, Up0, as1, ad1, Up1, as2, ad2, Up2,
        dsts, cnt, E);

    const int NB = (N + 1023) / 1024;
    scan1_kernel<<<NB, 1024, 0, stream>>>(cnt, rowptr, bsum, N);
    scan2_kernel<<<1, 64, 0, stream>>>(bsum, NB);
    scan3_kernel<<<NB, 1024, 0, stream>>>(rowptr, bsum, cnt, N);
    fill_kernel<<<(E + 255) / 256, 256, 0, stream>>>(srcs, dsts, etyp, rowptr, cnt, pks, E, N);

    const int MB = (N + 127) / 128;
    const int MBp = ((MB + 7) / 8) * 8;
    const int MB2 = (N + 255) / 256;
    const int MBp2 = ((MB2 + 7) / 8) * 8;

    // layer 0: in=128 -> D=256, heads=4, LN+ELU
    mfma_gemm_big<<<dim3(MBp2 * 2 * NREL), 512, 0, stream>>>(
        xb, Wh0, Up0, xw, sb, db, N, 128, 256);
    agg_h4_kernel<true, bf16><<<(N + 3) / 4, 256, 0, stream>>>(
        rowptr, pks, xw, sb, db, ar0, bi0, g0, be0, h, N);

    // layer 1: in=256 -> D=256, heads=4, LN+ELU
    mfma_gemm_big<<<dim3(MBp2 * 2 * NREL), 512, 0, stream>>>(
        h, Wh1, Up1, xw, sb, db, N, 256, 256);
    agg_h4_kernel<true, bf16><<<(N + 3) / 4, 256, 0, stream>>>(
        rowptr, pks, xw, sb, db, ar1, bi1, g1, be1, h, N);

    // layer 2: in=256 -> D=64, heads=1, fp32 output
    mfma_gemm<64><<<dim3(MBp * 1 * NREL), 256, 0, stream>>>(
        h, Wh2, Up2, xw, sb, db, N, 256, 64);
    agg_h1_kernel<<<(N + 3) / 4, 256, 0, stream>>>(
        rowptr, pks, xw, sb, db, ar2, bi2, (float*)d_out, N);
}